// Round 2
// baseline (766.919 us; speedup 1.0000x reference)
//
#include <hip/hip_runtime.h>
#include <hip/hip_bf16.h>

#define BF16 __hip_bfloat16
typedef short bf16x8 __attribute__((ext_vector_type(8)));
typedef float f32x4  __attribute__((ext_vector_type(4)));
typedef unsigned int u32;

#define MFMA16(a, b, c) __builtin_amdgcn_mfma_f32_16x16x32_bf16(a, b, c, 0, 0, 0)

// B=1, SV=2048, SA=512, S=2560, D=1024, H=16, DH=64, F=4096, L=2

__device__ __forceinline__ void async16(const void* g, void* l) {
  __builtin_amdgcn_global_load_lds(
      (const __attribute__((address_space(1))) u32*)g,
      (__attribute__((address_space(3))) u32*)l, 16, 0, 0);
}

__device__ __forceinline__ u32 pkbf(float a, float b) {
  union { BF16 h; unsigned short s; } ua, ub;
  ua.h = __float2bfloat16(a); ub.h = __float2bfloat16(b);
  return (u32)ua.s | ((u32)ub.s << 16);
}

// ---------------- weight transpose + f32->bf16 cast ----------------
__global__ __launch_bounds__(256) void wtrans(const float* __restrict__ W,
                                              BF16* __restrict__ WT, int K, int N,
                                              size_t outZ) {
  __shared__ float t[32][33];
  const float* Wm = W + (size_t)K * N * blockIdx.z;
  BF16* Tm = WT + outZ * blockIdx.z;
  int n0 = blockIdx.x * 32, k0 = blockIdx.y * 32;
  int tx = threadIdx.x & 31, ty = threadIdx.x >> 5;
#pragma unroll
  for (int i = 0; i < 4; i++)
    t[ty + 8 * i][tx] = Wm[(size_t)(k0 + ty + 8 * i) * N + n0 + tx];
  __syncthreads();
#pragma unroll
  for (int i = 0; i < 4; i++)
    Tm[(size_t)(n0 + ty + 8 * i) * K + k0 + tx] = __float2bfloat16(t[tx][ty + 8 * i]);
}

// ---------------- fused qkv bias pack ----------------
__global__ __launch_bounds__(256) void packb(const float* __restrict__ bq,
                                             const float* __restrict__ bk,
                                             const float* __restrict__ bv,
                                             float* __restrict__ bqkv) {
  int i = blockIdx.x * 256 + threadIdx.x;  // 4*3072
  int s = i / 3072, c = i - s * 3072;
  float v = (c < 1024) ? bq[s * 1024 + c]
          : (c < 2048) ? bk[s * 1024 + c - 1024]
                       : bv[s * 1024 + c - 2048];
  bqkv[i] = v;
}

// ---------------- LayerNorm * (1+sc) + sh -> bf16 ----------------
__global__ __launch_bounds__(256) void ln_mod(const float* __restrict__ x,
                                              BF16* __restrict__ out,
                                              const float* __restrict__ mod,
                                              const float* __restrict__ tmv,
                                              const float* __restrict__ tma,
                                              int l, int ish, int isc) {
  int r = blockIdx.x;
  int e = (r >= 2048) ? 1 : 0;
  const float* tm = e ? tma : tmv;
  const float* mo = mod + (size_t)((e * 2 + l) * 6) * 1024;
  float4 v = ((const float4*)(x + (size_t)r * 1024))[threadIdx.x];
  float s = v.x + v.y + v.z + v.w;
  float s2 = v.x * v.x + v.y * v.y + v.z * v.z + v.w * v.w;
#pragma unroll
  for (int off = 32; off >= 1; off >>= 1) {
    s += __shfl_down(s, off);
    s2 += __shfl_down(s2, off);
  }
  __shared__ float red[8];
  int lane = threadIdx.x & 63, w = threadIdx.x >> 6;
  if (lane == 0) { red[w] = s; red[4 + w] = s2; }
  __syncthreads();
  s = red[0] + red[1] + red[2] + red[3];
  s2 = red[4] + red[5] + red[6] + red[7];
  float mu = s * (1.f / 1024.f);
  float var = s2 * (1.f / 1024.f) - mu * mu;
  float inv = rsqrtf(var + 1e-6f);
  int c = threadIdx.x * 4;
  BF16* o = out + (size_t)r * 1024 + c;
  float xv[4] = {v.x, v.y, v.z, v.w};
#pragma unroll
  for (int k = 0; k < 4; k++) {
    float sc = mo[isc * 1024 + c + k] + tm[isc * 1024 + c + k];
    float sh = mo[ish * 1024 + c + k] + tm[ish * 1024 + c + k];
    o[k] = __float2bfloat16((xv[k] - mu) * inv * (1.f + sc) + sh);
  }
}

// ---------------- RMSNorm + gain + RoPE, reads fused qkv (stride 3072) ----------------
// Q rows are pre-scaled by 0.125*log2(e) so flash uses exp2 with raw dot products.
__global__ __launch_bounds__(256) void qk_post(const float* __restrict__ qkv,
                                               const float* __restrict__ gq,
                                               const float* __restrict__ gk,
                                               BF16* __restrict__ Qb, BF16* __restrict__ Kb,
                                               const float* __restrict__ vfreq,
                                               const float* __restrict__ afreq, int l) {
  int r = blockIdx.x;
  int which = blockIdx.y;
  const float* src = qkv + (size_t)r * 3072 + which * 1024;
  int e = (r >= 2048) ? 1 : 0;
  const float* g = (which ? gk : gq) + (size_t)(e * 2 + l) * 1024;
  BF16* dst = which ? Kb : Qb;
  const float* fr = e ? (afreq + (size_t)(r - 2048) * 32) : (vfreq + (size_t)r * 32);
  float4 v = ((const float4*)src)[threadIdx.x];
  float s2 = v.x * v.x + v.y * v.y + v.z * v.z + v.w * v.w;
#pragma unroll
  for (int off = 32; off >= 1; off >>= 1) s2 += __shfl_down(s2, off);
  __shared__ float red[4];
  int lane = threadIdx.x & 63, w = threadIdx.x >> 6;
  if (lane == 0) red[w] = s2;
  __syncthreads();
  s2 = red[0] + red[1] + red[2] + red[3];
  float inv = rsqrtf(s2 * (1.f / 1024.f) + 1e-6f);
  if (which == 0) inv *= 0.125f * 1.44269504f;  // fold softmax scale into Q
  int c = threadIdx.x * 4;
  float xe0 = v.x * inv * g[c], xo0 = v.y * inv * g[c + 1];
  float xe1 = v.z * inv * g[c + 2], xo1 = v.w * inv * g[c + 3];
  int p0 = (c & 63) >> 1;
  float c0, s0, c1, s1;
  __sincosf(fr[p0], &s0, &c0);
  __sincosf(fr[p0 + 1], &s1, &c1);
  int h = c >> 6;
  size_t o = ((size_t)h * 2560 + r) * 64 + (c & 63);
  dst[o + 0] = __float2bfloat16(xe0 * c0 - xo0 * s0);
  dst[o + 1] = __float2bfloat16(xe0 * s0 + xo0 * c0);
  dst[o + 2] = __float2bfloat16(xe1 * c1 - xo1 * s1);
  dst[o + 3] = __float2bfloat16(xe1 * s1 + xo1 * c1);
}

// ---------------- V (from qkv col 2048, stride 3072) -> V^T (H*DH, S) bf16 ----------------
__global__ __launch_bounds__(256) void vpost(const float* __restrict__ qkv,
                                             BF16* __restrict__ VT) {
  __shared__ float t[32][33];
  int r0 = blockIdx.x * 32, c0 = blockIdx.y * 32;
  int tx = threadIdx.x & 31, ty = threadIdx.x >> 5;
#pragma unroll
  for (int i = 0; i < 4; i++)
    t[ty + 8 * i][tx] = qkv[(size_t)(r0 + ty + 8 * i) * 3072 + 2048 + c0 + tx];
  __syncthreads();
#pragma unroll
  for (int i = 0; i < 4; i++)
    VT[(size_t)(c0 + ty + 8 * i) * 2560 + r0 + tx] = __float2bfloat16(t[tx][ty + 8 * i]);
}

// ---------------- GEMM v2: C = A(2560xK) * B^T(NxK), expert-aware, BK=64 ----------------
template <int EPI, int KS>
__global__ __launch_bounds__(256) void gemm2(const BF16* __restrict__ A,
                                             const BF16* __restrict__ Bw, size_t Bestride,
                                             const float* __restrict__ bias, int biasE,
                                             void* __restrict__ out, float* __restrict__ part,
                                             int N, int K) {
  __shared__ BF16 As[128 * 64];
  __shared__ BF16 Bs[128 * 64];
  int flat = blockIdx.x + blockIdx.y * gridDim.x;
  int xcd = flat & 7, slot = flat >> 3;
  int bx = slot % gridDim.x;
  int by = (slot / gridDim.x) * 8 + xcd;
  int m0 = bx * 128, n0 = by * 128;
  int e = (m0 >= 2048);
  const BF16* Ab = A + (size_t)m0 * K;
  const BF16* Bb = Bw + (e ? Bestride : 0) + (size_t)n0 * K;
  int kz0 = blockIdx.z * (K / KS), kz1 = kz0 + K / KS;
  int tid = threadIdx.x, lane = tid & 63, w = tid >> 6;
  int wr = w & 1, wc = w >> 1;
  int m15 = lane & 15, q4 = lane >> 4;
  int L[4], rS[4], cS[4];
#pragma unroll
  for (int i = 0; i < 4; i++) {
    L[i] = w * 256 + i * 64 + lane;
    rS[i] = L[i] >> 3;
    cS[i] = (L[i] & 7) ^ (rS[i] & 7);
  }
  f32x4 acc[4][4] = {};
  for (int k0 = kz0; k0 < kz1; k0 += 64) {
    __syncthreads();
#pragma unroll
    for (int i = 0; i < 4; i++) {
      async16(Ab + (size_t)rS[i] * K + k0 + cS[i] * 8, &As[L[i] * 8]);
      async16(Bb + (size_t)rS[i] * K + k0 + cS[i] * 8, &Bs[L[i] * 8]);
    }
    __syncthreads();
#pragma unroll
    for (int kk = 0; kk < 2; kk++) {
      int pos = ((kk * 4 + q4) ^ (m15 & 7)) * 8;
      bf16x8 af[4], bv[4];
#pragma unroll
      for (int i = 0; i < 4; i++) af[i] = *(const bf16x8*)&As[(wr * 64 + i * 16 + m15) * 64 + pos];
#pragma unroll
      for (int j = 0; j < 4; j++) bv[j] = *(const bf16x8*)&Bs[(wc * 64 + j * 16 + m15) * 64 + pos];
#pragma unroll
      for (int i = 0; i < 4; i++)
#pragma unroll
        for (int j = 0; j < 4; j++)
          acc[i][j] = MFMA16(af[i], bv[j], acc[i][j]);
    }
  }
#pragma unroll
  for (int i = 0; i < 4; i++) {
    int row = m0 + wr * 64 + 16 * i + q4 * 4;
#pragma unroll
    for (int j = 0; j < 4; j++) {
      int col = n0 + wc * 64 + 16 * j + m15;
      float b = (EPI == 3) ? 0.f : bias[e * biasE + col];
#pragma unroll
      for (int rg = 0; rg < 4; rg++) {
        float v = acc[i][j][rg] + b;
        size_t idx = (size_t)(row + rg) * N + col;
        if (EPI == 0) {
          ((float*)out)[idx] = v;
        } else if (EPI == 1) {
          // gelu(tanh) == v / (1 + exp2(-2*log2e*u)); exact at +-inf, monotone
          float u = v * (0.7978845608f + 0.0356774081f * v * v);
          float d = 1.f + exp2f(-2.8853900818f * u);
          ((BF16*)out)[idx] = __float2bfloat16(v * __builtin_amdgcn_rcpf(d));
        } else {
          part[(size_t)blockIdx.z * 2560 * N + idx] = v;
        }
      }
    }
  }
}

// ---------------- split-K combine + gated residual ----------------
template <int KS>
__global__ __launch_bounds__(256) void combine(const float* __restrict__ part,
                                               const float* __restrict__ biasL,
                                               const float* __restrict__ modp, int gi, int l,
                                               const float* __restrict__ tmv,
                                               const float* __restrict__ tma,
                                               const float* __restrict__ xin,
                                               float* __restrict__ xout) {
  int r = blockIdx.x, e = (r >= 2048) ? 1 : 0;
  int c = threadIdx.x * 4;
  float4 s = {0.f, 0.f, 0.f, 0.f};
#pragma unroll
  for (int z = 0; z < KS; z++) {
    float4 p = *(const float4*)&part[((size_t)z * 2560 + r) * 1024 + c];
    s.x += p.x; s.y += p.y; s.z += p.z; s.w += p.w;
  }
  float4 b = *(const float4*)&biasL[e * 2048 + c];
  const float* tm = e ? tma : tmv;
  float4 gm = *(const float4*)&modp[(size_t)((e * 2 + l) * 6 + gi) * 1024 + c];
  float4 gt = *(const float4*)&tm[gi * 1024 + c];
  float4 xi = *(const float4*)&xin[(size_t)r * 1024 + c];
  float4 o;
  o.x = xi.x + (gm.x + gt.x) * (s.x + b.x);
  o.y = xi.y + (gm.y + gt.y) * (s.y + b.y);
  o.z = xi.z + (gm.z + gt.z) * (s.z + b.z);
  o.w = xi.w + (gm.w + gt.w) * (s.w + b.w);
  *(float4*)&xout[(size_t)r * 1024 + c] = o;
}

// ---------------- flash v5: 4-way KV split, lane-local defer-max, partial l ----------------
// Qb (pre-scaled),Kb: (H,S,DH) bf16; VT: (H,DH,S) bf16
// grid (40, 16, 4): z = KV quarter. Unnormalized O (f32) + (m,l) partials.
// z 0/1 partials -> OpA (qkv scratch), z 2/3 -> OpB (hbf scratch).
// LDS = 16K(K) + 16K(V) + 8K(P) = 40960 -> 4 blocks/CU.
__global__ __launch_bounds__(256) void flash5(const BF16* __restrict__ Qb,
                                              const BF16* __restrict__ Kb,
                                              const BF16* __restrict__ VT,
                                              float* __restrict__ OpA,
                                              float* __restrict__ OpB,
                                              float* __restrict__ ml) {
  const int S = 2560;
  const size_t ZO = 16ull * 40 * 4096;
  const size_t ZM = 16ull * 40 * 128;
  __shared__ BF16 Ks[2][64 * 64];
  __shared__ BF16 Vs[2][64 * 64];
  __shared__ BF16 Ps[4][16 * 64];  // wave-private P, stride 64, XOR-swizzled
  int tid = threadIdx.x, lane = tid & 63, w = tid >> 6;
  int h = blockIdx.y, q0 = blockIdx.x * 64, kz = blockIdx.z;
  int m15 = lane & 15, q4 = lane >> 4;
  int actq = (q0 >= 2048);
  int nt = actq ? ((q0 >> 6) + 1) : 32;
  int tb = (kz * nt) >> 2, te = ((kz + 1) * nt) >> 2;
  const BF16* qrow = Qb + ((size_t)h * S + q0 + w * 16 + m15) * 64;
  bf16x8 qf0 = *(const bf16x8*)(qrow + q4 * 8);
  bf16x8 qf1 = *(const bf16x8*)(qrow + 32 + q4 * 8);
  const BF16* kbase = Kb + (size_t)h * S * 64;
  const BF16* vbase = VT + (size_t)h * 64 * S;
  // staging: 64x64 tile = 512 chunks; 2 per thread
  int L0 = w * 128 + lane, L1 = L0 + 64;
  int r0 = L0 >> 3, c0 = (L0 & 7) ^ (r0 & 7);
  int r1 = L1 >> 3, c1 = (L1 & 7) ^ (r1 & 7);
  {
    const BF16* kg = kbase + (size_t)tb * 64 * 64;
    const BF16* vg = vbase + (size_t)tb * 64;
    async16(kg + (size_t)r0 * 64 + c0 * 8, &Ks[0][L0 * 8]);
    async16(kg + (size_t)r1 * 64 + c1 * 8, &Ks[0][L1 * 8]);
    async16(vg + (size_t)r0 * S + c0 * 8, &Vs[0][L0 * 8]);
    async16(vg + (size_t)r1 * S + c1 * 8, &Vs[0][L1 * 8]);
  }
  f32x4 oa[4] = {};
  float m_i = -1e30f, l_i = 0.f;  // l_i: per-lane partial (reduced at end)
  int colq = q0 + w * 16 + m15;
  char* Pw = (char*)&Ps[w][0];
  int prow = m15 * 128;            // byte offset of this q's P row
  int pswz = (m15 & 7) << 4;       // XOR swizzle (bits 4-6 of row-local byte)
  int x0 = (q4 ^ (m15 & 7)) * 8, x1 = ((4 + q4) ^ (m15 & 7)) * 8;
  __syncthreads();
  for (int t = tb; t < te; t++) {
    int cur = (t - tb) & 1;
    if (t + 1 < te) {
      int nb = cur ^ 1;
      const BF16* kg = kbase + (size_t)(t + 1) * 64 * 64;
      const BF16* vg = vbase + (size_t)(t + 1) * 64;
      async16(kg + (size_t)r0 * 64 + c0 * 8, &Ks[nb][L0 * 8]);
      async16(kg + (size_t)r1 * 64 + c1 * 8, &Ks[nb][L1 * 8]);
      async16(vg + (size_t)r0 * S + c0 * 8, &Vs[nb][L0 * 8]);
      async16(vg + (size_t)r1 * S + c1 * 8, &Vs[nb][L1 * 8]);
    }
    // S^T = K * Q^T (col = q = m15, row = kv)
    f32x4 st[4];
    __builtin_amdgcn_s_setprio(1);
#pragma unroll
    for (int jt = 0; jt < 4; jt++) {
      int row = (jt * 16 + m15) * 64;
      bf16x8 kf0 = *(const bf16x8*)&Ks[cur][row + x0];
      bf16x8 kf1 = *(const bf16x8*)&Ks[cur][row + x1];
      f32x4 zz = {};
      zz = MFMA16(kf0, qf0, zz);
      st[jt] = MFMA16(kf1, qf1, zz);
    }
    __builtin_amdgcn_s_setprio(0);
    float mx = -1e30f;  // per-lane max (covers this lane's 16 scores)
    if (actq && t == nt - 1) {
#pragma unroll
      for (int jt = 0; jt < 4; jt++)
#pragma unroll
        for (int rg = 0; rg < 4; rg++) {
          int rowkv = t * 64 + jt * 16 + q4 * 4 + rg;
          if (rowkv > colq) st[jt][rg] = -1e30f;
          mx = fmaxf(mx, st[jt][rg]);
        }
    } else {
#pragma unroll
      for (int jt = 0; jt < 4; jt++) {
        mx = fmaxf(fmaxf(mx, st[jt][0]), st[jt][1]);  // v_max3
        mx = fmaxf(fmaxf(mx, st[jt][2]), st[jt][3]);
      }
    }
    // defer-max: lane-local check is sufficient (union of lanes covers each row).
    // Cross-lane reduce only on the rare rescale path.
    if (!__all(mx <= m_i + 8.f)) {
      float m2 = fmaxf(mx, __shfl_xor(mx, 16));
      m2 = fmaxf(m2, __shfl_xor(m2, 32));
      float mn = fmaxf(m_i, m2);
      float al = exp2f(m_i - mn);
      m_i = mn;
      l_i *= al;
      float alr[4];
#pragma unroll
      for (int rg = 0; rg < 4; rg++) alr[rg] = __shfl(al, q4 * 4 + rg);
#pragma unroll
      for (int dt = 0; dt < 4; dt++)
#pragma unroll
        for (int rg = 0; rg < 4; rg++) oa[dt][rg] *= alr[rg];
    }
    float rs = 0.f;
#pragma unroll
    for (int jt = 0; jt < 4; jt++) {
      float p0 = exp2f(st[jt][0] - m_i), p1 = exp2f(st[jt][1] - m_i);
      float p2 = exp2f(st[jt][2] - m_i), p3 = exp2f(st[jt][3] - m_i);
      rs += (p0 + p1) + (p2 + p3);
      uint2 pr = {pkbf(p0, p1), pkbf(p2, p3)};
      *(uint2*)(Pw + prow + ((jt * 32 + q4 * 8) ^ pswz)) = pr;  // P[q][kv], b64
    }
    l_i += rs;
    // O += P * V  (A = P from wave-private swizzled LDS, B = V^T rows)
    bf16x8 pf0 = *(const bf16x8*)(Pw + prow + ((q4 * 16) ^ pswz));
    bf16x8 pf1 = *(const bf16x8*)(Pw + prow + ((64 + q4 * 16) ^ pswz));
    __builtin_amdgcn_s_setprio(1);
#pragma unroll
    for (int dt = 0; dt < 4; dt++) {
      int vr = (dt * 16 + m15) * 64;
      bf16x8 vf0 = *(const bf16x8*)&Vs[cur][vr + x0];
      bf16x8 vf1 = *(const bf16x8*)&Vs[cur][vr + x1];
      oa[dt] = MFMA16(pf0, vf0, oa[dt]);
      oa[dt] = MFMA16(pf1, vf1, oa[dt]);
    }
    __builtin_amdgcn_s_setprio(0);
    __syncthreads();
  }
  // reduce partial l across the q-group, then store partial O (f32) + m,l
  l_i += __shfl_xor(l_i, 16);
  l_i += __shfl_xor(l_i, 32);
  float* Op = (kz < 2) ? (OpA + (size_t)kz * ZO) : (OpB + (size_t)(kz - 2) * ZO);
  size_t ob = ((size_t)h * 40 + blockIdx.x) * 4096;
#pragma unroll
  for (int dt = 0; dt < 4; dt++)
#pragma unroll
    for (int rg = 0; rg < 4; rg++)
      Op[ob + (size_t)(w * 16 + q4 * 4 + rg) * 64 + dt * 16 + m15] = oa[dt][rg];
  if (q4 == 0) {
    float* mp = ml + (size_t)kz * ZM + ((size_t)h * 40 + blockIdx.x) * 128;
    mp[w * 16 + m15] = m_i;
    mp[64 + w * 16 + m15] = l_i;
  }
}

// ---------------- merge the four KV-quarter partials -> Obf bf16 ----------------
__global__ __launch_bounds__(256) void fcomb4(const float* __restrict__ OpA,
                                              const float* __restrict__ OpB,
                                              const float* __restrict__ ml,
                                              BF16* __restrict__ O) {
  int qt = blockIdx.x, h = blockIdx.y;
  int q = threadIdx.x >> 2;          // 0..63
  int d0 = (threadIdx.x & 3) * 16;   // 16 floats per thread
  const size_t ZO = 16ull * 40 * 4096;
  const size_t ZM = 16ull * 40 * 128;
  size_t tile = (size_t)h * 40 + qt;
  size_t base = tile * 4096 + (size_t)q * 64 + d0;
  size_t mb = tile * 128 + q;
  float m[4], lv[4];
#pragma unroll
  for (int z = 0; z < 4; z++) {
    m[z] = ml[z * ZM + mb];
    lv[z] = ml[z * ZM + mb + 64];
  }
  float M = fmaxf(fmaxf(m[0], m[1]), fmaxf(m[2], m[3]));
  float wz[4];
  float den = 0.f;
#pragma unroll
  for (int z = 0; z < 4; z++) {
    wz[z] = exp2f(m[z] - M);
    den += wz[z] * lv[z];
  }
  float r = 1.f / den;
#pragma unroll
  for (int z = 0; z < 4; z++) wz[z] *= r;
  const float* P0 = OpA + base;
  const float* P1 = OpA + ZO + base;
  const float* P2 = OpB + base;
  const float* P3 = OpB + ZO + base;
  BF16* orow = O + (size_t)(qt * 64 + q) * 1024 + h * 64 + d0;
#pragma unroll
  for (int i = 0; i < 4; i++) {
    float4 a0 = *(const float4*)&P0[i * 4];
    float4 a1 = *(const float4*)&P1[i * 4];
    float4 a2 = *(const float4*)&P2[i * 4];
    float4 a3 = *(const float4*)&P3[i * 4];
    float vx = wz[0] * a0.x + wz[1] * a1.x + wz[2] * a2.x + wz[3] * a3.x;
    float vy = wz[0] * a0.y + wz[1] * a1.y + wz[2] * a2.y + wz[3] * a3.y;
    float vzv = wz[0] * a0.z + wz[1] * a1.z + wz[2] * a2.z + wz[3] * a3.z;
    float vw = wz[0] * a0.w + wz[1] * a1.w + wz[2] * a2.w + wz[3] * a3.w;
    uint2 pr = {pkbf(vx, vy), pkbf(vzv, vw)};
    *(uint2*)(orow + i * 4) = pr;
  }
}

// ---------------- host ----------------
extern "C" void kernel_launch(void* const* d_in, const int* in_sizes, int n_in,
                              void* d_out, int out_size, void* d_ws, size_t ws_size,
                              hipStream_t stream) {
  (void)in_sizes; (void)n_in; (void)out_size; (void)ws_size;
  const float* vid  = (const float*)d_in[0];
  const float* act  = (const float*)d_in[1];
  const float* vfr  = (const float*)d_in[2];
  const float* afr  = (const float*)d_in[3];
  const float* tmv  = (const float*)d_in[4];
  const float* tma  = (const float*)d_in[5];
  const float* Wq   = (const float*)d_in[6];
  const float* Wk   = (const float*)d_in[7];
  const float* Wv   = (const float*)d_in[8];
  const float* Wo   = (const float*)d_in[9];
  const float* bq   = (const float*)d_in[10];
  const float* bk   = (const float*)d_in[11];
  const float* bv   = (const float*)d_in[12];
  const float* bo   = (const float*)d_in[13];
  const float* gq   = (const float*)d_in[14];
  const float* gk   = (const float*)d_in[15];
  const float* modp = (const float*)d_in[16];
  const float* W1   = (const float*)d_in[17];
  const float* b1   = (const float*)d_in[18];
  const float* W2   = (const float*)d_in[19];
  const float* b2   = (const float*)d_in[20];

  char* p = (char*)d_ws;
  auto carve = [&](size_t bytes) {
    char* r = p;
    p += (bytes + 255) & ~(size_t)255;
    return r;
  };
  BF16* WqkvT = (BF16*)carve(4ull * 3072 * 1024 * 2);
  BF16* WoT   = (BF16*)carve(4ull * 1024 * 1024 * 2);
  BF16* W1T   = (BF16*)carve(4ull * 4096 * 1024 * 2);
  BF16* W2T   = (BF16*)carve(4ull * 1024 * 4096 * 2);
  float* bqkv = (float*)carve(4ull * 3072 * 4);
  float* x    = (float*)carve(2560ull * 1024 * 4);
  BF16* abf   = (BF16*)carve(2560ull * 1024 * 2);
  float* qkv  = (float*)carve(2560ull * 3072 * 4);
  BF16* Qb    = (BF16*)carve(2560ull * 1024 * 2);
  BF16* Kb    = (BF16*)carve(2560ull * 1024 * 2);
  float* part = qkv;  // aliases qkv/Qb/Kb region (dead when partials are live)
  const size_t ZO = 16ull * 40 * 4096;
  float* OpA = qkv;               // flash partials z=0,1: 21.0MB (qkv dead after qk_post/vpost)
  float* mlb = qkv + 2ull * ZO;   // 1.3MB, still inside qkv region
  BF16* VTb   = (BF16*)carve(2560ull * 1024 * 2);
  BF16* Obf   = (BF16*)carve(2560ull * 1024 * 2);
  BF16* mibf  = (BF16*)carve(2560ull * 1024 * 2);
  BF16* hbf   = (BF16*)carve(2560ull * 4096 * 2);
  float* OpB = (float*)hbf;       // flash partials z=2,3: 21.0MB (hbf dead during attention)

  hipMemcpyAsync(x, vid, 2048ull * 1024 * 4, hipMemcpyDeviceToDevice, stream);
  hipMemcpyAsync(x + 2048ull * 1024, act, 512ull * 1024 * 4, hipMemcpyDeviceToDevice, stream);

  const size_t S3 = 3072ull * 1024;
  wtrans<<<dim3(32, 32, 4), 256, 0, stream>>>(Wq, WqkvT, 1024, 1024, S3);
  wtrans<<<dim3(32, 32, 4), 256, 0, stream>>>(Wk, WqkvT + 1024ull * 1024, 1024, 1024, S3);
  wtrans<<<dim3(32, 32, 4), 256, 0, stream>>>(Wv, WqkvT + 2048ull * 1024, 1024, 1024, S3);
  wtrans<<<dim3(32, 32, 4), 256, 0, stream>>>(Wo, WoT, 1024, 1024, 1024ull * 1024);
  wtrans<<<dim3(128, 32, 4), 256, 0, stream>>>(W1, W1T, 1024, 4096, 4096ull * 1024);
  wtrans<<<dim3(32, 128, 4), 256, 0, stream>>>(W2, W2T, 4096, 1024, 1024ull * 4096);
  packb<<<48, 256, 0, stream>>>(bq, bk, bv, bqkv);

  for (int l = 0; l < 2; l++) {
    ln_mod<<<2560, 256, 0, stream>>>(x, abf, modp, tmv, tma, l, 0, 1);
    gemm2<0, 1><<<dim3(20, 24, 1), 256, 0, stream>>>(
        abf, WqkvT + (size_t)l * S3, 2 * S3, bqkv + l * 3072, 6144, qkv, nullptr, 3072, 1024);
    qk_post<<<dim3(2560, 2), 256, 0, stream>>>(qkv, gq, gk, Qb, Kb, vfr, afr, l);
    vpost<<<dim3(80, 32), 256, 0, stream>>>(qkv, VTb);
    flash5<<<dim3(40, 16, 4), 256, 0, stream>>>(Qb, Kb, VTb, OpA, OpB, mlb);
    fcomb4<<<dim3(40, 16), 256, 0, stream>>>(OpA, OpB, mlb, Obf);
    gemm2<3, 2><<<dim3(20, 8, 2), 256, 0, stream>>>(
        Obf, WoT + (size_t)l * 1024 * 1024, 2ull * 1024 * 1024, nullptr, 0, nullptr, part,
        1024, 1024);
    combine<2><<<2560, 256, 0, stream>>>(part, bo + l * 1024, modp, 2, l, tmv, tma, x, x);
    ln_mod<<<2560, 256, 0, stream>>>(x, mibf, modp, tmv, tma, l, 3, 4);
    gemm2<1, 1><<<dim3(20, 32, 1), 256, 0, stream>>>(
        mibf, W1T + (size_t)l * 4096 * 1024, 2ull * 4096 * 1024, b1 + l * 4096, 8192, hbf,
        nullptr, 4096, 1024);
    gemm2<3, 4><<<dim3(20, 8, 4), 256, 0, stream>>>(
        hbf, W2T + (size_t)l * 4096 * 1024, 2ull * 4096 * 1024, nullptr, 0, nullptr, part,
        1024, 4096);
    combine<4><<<2560, 256, 0, stream>>>(part, b2 + l * 1024, modp, 5, l, tmv, tma, x,
                                         (l == 1) ? (float*)d_out : x);
  }
}

// Round 3
// 750.852 us; speedup vs baseline: 1.0214x; 1.0214x over previous
//
#include <hip/hip_runtime.h>
#include <hip/hip_bf16.h>

#define BF16 __hip_bfloat16
typedef short bf16x8 __attribute__((ext_vector_type(8)));
typedef float f32x4  __attribute__((ext_vector_type(4)));
typedef unsigned int u32;

#define MFMA16(a, b, c) __builtin_amdgcn_mfma_f32_16x16x32_bf16(a, b, c, 0, 0, 0)

// B=1, SV=2048, SA=512, S=2560, D=1024, H=16, DH=64, F=4096, L=2

__device__ __forceinline__ void async16(const void* g, void* l) {
  __builtin_amdgcn_global_load_lds(
      (const __attribute__((address_space(1))) u32*)g,
      (__attribute__((address_space(3))) u32*)l, 16, 0, 0);
}

__device__ __forceinline__ u32 pkbf(float a, float b) {
  union { BF16 h; unsigned short s; } ua, ub;
  ua.h = __float2bfloat16(a); ub.h = __float2bfloat16(b);
  return (u32)ua.s | ((u32)ub.s << 16);
}

__device__ __forceinline__ float bf2f(short s) {
  union { float f; u32 u; } v;
  v.u = ((u32)(unsigned short)s) << 16;
  return v.f;
}

// ---------------- weight transpose + f32->bf16 cast ----------------
__global__ __launch_bounds__(256) void wtrans(const float* __restrict__ W,
                                              BF16* __restrict__ WT, int K, int N,
                                              size_t outZ) {
  __shared__ float t[32][33];
  const float* Wm = W + (size_t)K * N * blockIdx.z;
  BF16* Tm = WT + outZ * blockIdx.z;
  int n0 = blockIdx.x * 32, k0 = blockIdx.y * 32;
  int tx = threadIdx.x & 31, ty = threadIdx.x >> 5;
#pragma unroll
  for (int i = 0; i < 4; i++)
    t[ty + 8 * i][tx] = Wm[(size_t)(k0 + ty + 8 * i) * N + n0 + tx];
  __syncthreads();
#pragma unroll
  for (int i = 0; i < 4; i++)
    Tm[(size_t)(n0 + ty + 8 * i) * K + k0 + tx] = __float2bfloat16(t[tx][ty + 8 * i]);
}

// merged Wq/Wk/Wv transpose: z in [0,12): mat = z>>2, expert = z&3
__global__ __launch_bounds__(256) void wtransq(const float* __restrict__ Wq,
                                               const float* __restrict__ Wk,
                                               const float* __restrict__ Wv,
                                               BF16* __restrict__ WT) {
  __shared__ float t[32][33];
  int mat = blockIdx.z >> 2, ex = blockIdx.z & 3;
  const float* Wm = (mat == 0 ? Wq : mat == 1 ? Wk : Wv) + (size_t)ex * 1024 * 1024;
  BF16* Tm = WT + (size_t)ex * 3072 * 1024 + (size_t)mat * 1024 * 1024;
  int n0 = blockIdx.x * 32, k0 = blockIdx.y * 32;
  int tx = threadIdx.x & 31, ty = threadIdx.x >> 5;
#pragma unroll
  for (int i = 0; i < 4; i++)
    t[ty + 8 * i][tx] = Wm[(size_t)(k0 + ty + 8 * i) * 1024 + n0 + tx];
  __syncthreads();
#pragma unroll
  for (int i = 0; i < 4; i++)
    Tm[(size_t)(n0 + ty + 8 * i) * 1024 + k0 + tx] = __float2bfloat16(t[tx][ty + 8 * i]);
}

// ---------------- fused qkv bias pack ----------------
__global__ __launch_bounds__(256) void packb(const float* __restrict__ bq,
                                             const float* __restrict__ bk,
                                             const float* __restrict__ bv,
                                             float* __restrict__ bqkv) {
  int i = blockIdx.x * 256 + threadIdx.x;  // 4*3072
  int s = i / 3072, c = i - s * 3072;
  float v = (c < 1024) ? bq[s * 1024 + c]
          : (c < 2048) ? bk[s * 1024 + c - 1024]
                       : bv[s * 1024 + c - 2048];
  bqkv[i] = v;
}

// ---------------- LayerNorm * (1+sc) + sh -> bf16 (row-split input) ----------------
__global__ __launch_bounds__(256) void ln_mod(const float* __restrict__ xV,
                                              const float* __restrict__ xA,
                                              BF16* __restrict__ out,
                                              const float* __restrict__ mod,
                                              const float* __restrict__ tmv,
                                              const float* __restrict__ tma,
                                              int l, int ish, int isc) {
  int r = blockIdx.x;
  int e = (r >= 2048) ? 1 : 0;
  const float* xrow = e ? (xA + (size_t)(r - 2048) * 1024) : (xV + (size_t)r * 1024);
  const float* tm = e ? tma : tmv;
  const float* mo = mod + (size_t)((e * 2 + l) * 6) * 1024;
  float4 v = ((const float4*)xrow)[threadIdx.x];
  float s = v.x + v.y + v.z + v.w;
  float s2 = v.x * v.x + v.y * v.y + v.z * v.z + v.w * v.w;
#pragma unroll
  for (int off = 32; off >= 1; off >>= 1) {
    s += __shfl_down(s, off);
    s2 += __shfl_down(s2, off);
  }
  __shared__ float red[8];
  int lane = threadIdx.x & 63, w = threadIdx.x >> 6;
  if (lane == 0) { red[w] = s; red[4 + w] = s2; }
  __syncthreads();
  s = red[0] + red[1] + red[2] + red[3];
  s2 = red[4] + red[5] + red[6] + red[7];
  float mu = s * (1.f / 1024.f);
  float var = s2 * (1.f / 1024.f) - mu * mu;
  float inv = rsqrtf(var + 1e-6f);
  int c = threadIdx.x * 4;
  BF16* o = out + (size_t)r * 1024 + c;
  float xv[4] = {v.x, v.y, v.z, v.w};
#pragma unroll
  for (int k = 0; k < 4; k++) {
    float sc = mo[isc * 1024 + c + k] + tm[isc * 1024 + c + k];
    float sh = mo[ish * 1024 + c + k] + tm[ish * 1024 + c + k];
    o[k] = __float2bfloat16((xv[k] - mu) * inv * (1.f + sc) + sh);
  }
}

// ---------------- RMSNorm + gain + RoPE, reads fused qkv (stride 3072) ----------------
// Q rows are pre-scaled by 0.125*log2(e) so flash uses exp2 with raw dot products.
__global__ __launch_bounds__(256) void qk_post(const float* __restrict__ qkv,
                                               const float* __restrict__ gq,
                                               const float* __restrict__ gk,
                                               BF16* __restrict__ Qb, BF16* __restrict__ Kb,
                                               const float* __restrict__ vfreq,
                                               const float* __restrict__ afreq, int l) {
  int r = blockIdx.x;
  int which = blockIdx.y;
  const float* src = qkv + (size_t)r * 3072 + which * 1024;
  int e = (r >= 2048) ? 1 : 0;
  const float* g = (which ? gk : gq) + (size_t)(e * 2 + l) * 1024;
  BF16* dst = which ? Kb : Qb;
  const float* fr = e ? (afreq + (size_t)(r - 2048) * 32) : (vfreq + (size_t)r * 32);
  float4 v = ((const float4*)src)[threadIdx.x];
  float s2 = v.x * v.x + v.y * v.y + v.z * v.z + v.w * v.w;
#pragma unroll
  for (int off = 32; off >= 1; off >>= 1) s2 += __shfl_down(s2, off);
  __shared__ float red[4];
  int lane = threadIdx.x & 63, w = threadIdx.x >> 6;
  if (lane == 0) red[w] = s2;
  __syncthreads();
  s2 = red[0] + red[1] + red[2] + red[3];
  float inv = rsqrtf(s2 * (1.f / 1024.f) + 1e-6f);
  if (which == 0) inv *= 0.125f * 1.44269504f;  // fold softmax scale into Q
  int c = threadIdx.x * 4;
  float xe0 = v.x * inv * g[c], xo0 = v.y * inv * g[c + 1];
  float xe1 = v.z * inv * g[c + 2], xo1 = v.w * inv * g[c + 3];
  int p0 = (c & 63) >> 1;
  float c0, s0, c1, s1;
  __sincosf(fr[p0], &s0, &c0);
  __sincosf(fr[p0 + 1], &s1, &c1);
  int h = c >> 6;
  size_t o = ((size_t)h * 2560 + r) * 64 + (c & 63);
  dst[o + 0] = __float2bfloat16(xe0 * c0 - xo0 * s0);
  dst[o + 1] = __float2bfloat16(xe0 * s0 + xo0 * c0);
  dst[o + 2] = __float2bfloat16(xe1 * c1 - xo1 * s1);
  dst[o + 3] = __float2bfloat16(xe1 * s1 + xo1 * c1);
}

// ---------------- V (from qkv col 2048, stride 3072) -> V^T (H*DH, S) bf16 ----------------
__global__ __launch_bounds__(256) void vpost(const float* __restrict__ qkv,
                                             BF16* __restrict__ VT) {
  __shared__ float t[32][33];
  int r0 = blockIdx.x * 32, c0 = blockIdx.y * 32;
  int tx = threadIdx.x & 31, ty = threadIdx.x >> 5;
#pragma unroll
  for (int i = 0; i < 4; i++)
    t[ty + 8 * i][tx] = qkv[(size_t)(r0 + ty + 8 * i) * 3072 + 2048 + c0 + tx];
  __syncthreads();
#pragma unroll
  for (int i = 0; i < 4; i++)
    VT[(size_t)(c0 + ty + 8 * i) * 2560 + r0 + tx] = __float2bfloat16(t[tx][ty + 8 * i]);
}

// ---------------- GEMM v2: C = A(2560xK) * B^T(NxK), expert-aware, BK=64 ----------------
template <int EPI, int KS>
__global__ __launch_bounds__(256) void gemm2(const BF16* __restrict__ A,
                                             const BF16* __restrict__ Bw, size_t Bestride,
                                             const float* __restrict__ bias, int biasE,
                                             void* __restrict__ out, float* __restrict__ part,
                                             int N, int K) {
  __shared__ BF16 As[128 * 64];
  __shared__ BF16 Bs[128 * 64];
  int flat = blockIdx.x + blockIdx.y * gridDim.x;
  int xcd = flat & 7, slot = flat >> 3;
  int bx = slot % gridDim.x;
  int by = (slot / gridDim.x) * 8 + xcd;
  int m0 = bx * 128, n0 = by * 128;
  int e = (m0 >= 2048);
  const BF16* Ab = A + (size_t)m0 * K;
  const BF16* Bb = Bw + (e ? Bestride : 0) + (size_t)n0 * K;
  int kz0 = blockIdx.z * (K / KS), kz1 = kz0 + K / KS;
  int tid = threadIdx.x, lane = tid & 63, w = tid >> 6;
  int wr = w & 1, wc = w >> 1;
  int m15 = lane & 15, q4 = lane >> 4;
  int L[4], rS[4], cS[4];
#pragma unroll
  for (int i = 0; i < 4; i++) {
    L[i] = w * 256 + i * 64 + lane;
    rS[i] = L[i] >> 3;
    cS[i] = (L[i] & 7) ^ (rS[i] & 7);
  }
  f32x4 acc[4][4] = {};
  for (int k0 = kz0; k0 < kz1; k0 += 64) {
    __syncthreads();
#pragma unroll
    for (int i = 0; i < 4; i++) {
      async16(Ab + (size_t)rS[i] * K + k0 + cS[i] * 8, &As[L[i] * 8]);
      async16(Bb + (size_t)rS[i] * K + k0 + cS[i] * 8, &Bs[L[i] * 8]);
    }
    __syncthreads();
#pragma unroll
    for (int kk = 0; kk < 2; kk++) {
      int pos = ((kk * 4 + q4) ^ (m15 & 7)) * 8;
      bf16x8 af[4], bv[4];
#pragma unroll
      for (int i = 0; i < 4; i++) af[i] = *(const bf16x8*)&As[(wr * 64 + i * 16 + m15) * 64 + pos];
#pragma unroll
      for (int j = 0; j < 4; j++) bv[j] = *(const bf16x8*)&Bs[(wc * 64 + j * 16 + m15) * 64 + pos];
#pragma unroll
      for (int i = 0; i < 4; i++)
#pragma unroll
        for (int j = 0; j < 4; j++)
          acc[i][j] = MFMA16(af[i], bv[j], acc[i][j]);
    }
  }
#pragma unroll
  for (int i = 0; i < 4; i++) {
    int row = m0 + wr * 64 + 16 * i + q4 * 4;
#pragma unroll
    for (int j = 0; j < 4; j++) {
      int col = n0 + wc * 64 + 16 * j + m15;
      float b = (EPI == 3) ? 0.f : bias[e * biasE + col];
#pragma unroll
      for (int rg = 0; rg < 4; rg++) {
        float v = acc[i][j][rg] + b;
        size_t idx = (size_t)(row + rg) * N + col;
        if (EPI == 0) {
          ((float*)out)[idx] = v;
        } else if (EPI == 1) {
          // gelu(tanh) == v / (1 + exp2(-2*log2e*u)); exact at +-inf, monotone
          float u = v * (0.7978845608f + 0.0356774081f * v * v);
          float d = 1.f + exp2f(-2.8853900818f * u);
          ((BF16*)out)[idx] = __float2bfloat16(v * __builtin_amdgcn_rcpf(d));
        } else {
          part[(size_t)blockIdx.z * 2560 * N + idx] = v;
        }
      }
    }
  }
}

// ---------------- split-K combine + gated residual (+ fused next LayerNorm) ----------------
template <int KS, int LN>
__global__ __launch_bounds__(256) void combine_ln(const float* __restrict__ part,
                                                  const float* __restrict__ biasL,
                                                  const float* __restrict__ modp,
                                                  int gi, int lg, int ll, int ish, int isc,
                                                  const float* __restrict__ tmv,
                                                  const float* __restrict__ tma,
                                                  const float* __restrict__ xinV,
                                                  const float* __restrict__ xinA,
                                                  float* __restrict__ xout,
                                                  BF16* __restrict__ lnout) {
  int r = blockIdx.x, e = (r >= 2048) ? 1 : 0;
  int c = threadIdx.x * 4;
  float4 s = {0.f, 0.f, 0.f, 0.f};
#pragma unroll
  for (int z = 0; z < KS; z++) {
    float4 p = *(const float4*)&part[((size_t)z * 2560 + r) * 1024 + c];
    s.x += p.x; s.y += p.y; s.z += p.z; s.w += p.w;
  }
  float4 b = *(const float4*)&biasL[e * 2048 + c];
  const float* tm = e ? tma : tmv;
  float4 gm = *(const float4*)&modp[(size_t)((e * 2 + lg) * 6 + gi) * 1024 + c];
  float4 gt = *(const float4*)&tm[gi * 1024 + c];
  const float* xrow = e ? (xinA + (size_t)(r - 2048) * 1024) : (xinV + (size_t)r * 1024);
  float4 xi = *(const float4*)&xrow[c];
  float4 o;
  o.x = xi.x + (gm.x + gt.x) * (s.x + b.x);
  o.y = xi.y + (gm.y + gt.y) * (s.y + b.y);
  o.z = xi.z + (gm.z + gt.z) * (s.z + b.z);
  o.w = xi.w + (gm.w + gt.w) * (s.w + b.w);
  *(float4*)&xout[(size_t)r * 1024 + c] = o;
  if (LN) {
    float su = o.x + o.y + o.z + o.w;
    float s2 = o.x * o.x + o.y * o.y + o.z * o.z + o.w * o.w;
#pragma unroll
    for (int off = 32; off >= 1; off >>= 1) {
      su += __shfl_down(su, off);
      s2 += __shfl_down(s2, off);
    }
    __shared__ float red[8];
    int lane = threadIdx.x & 63, w = threadIdx.x >> 6;
    if (lane == 0) { red[w] = su; red[4 + w] = s2; }
    __syncthreads();
    su = red[0] + red[1] + red[2] + red[3];
    s2 = red[4] + red[5] + red[6] + red[7];
    float mu = su * (1.f / 1024.f);
    float var = s2 * (1.f / 1024.f) - mu * mu;
    float inv = rsqrtf(var + 1e-6f);
    const float* mo = modp + (size_t)((e * 2 + ll) * 6) * 1024;
    BF16* ob = lnout + (size_t)r * 1024 + c;
    float ov[4] = {o.x, o.y, o.z, o.w};
#pragma unroll
    for (int k = 0; k < 4; k++) {
      float sc = mo[isc * 1024 + c + k] + tm[isc * 1024 + c + k];
      float sh = mo[ish * 1024 + c + k] + tm[ish * 1024 + c + k];
      ob[k] = __float2bfloat16((ov[k] - mu) * inv * (1.f + sc) + sh);
    }
  }
}

// ---------------- flash v6: 4-way KV split, bf16 partials via LDS repack ----------------
// Qb (pre-scaled),Kb: (H,S,DH) bf16; VT: (H,DH,S) bf16
// grid (40, 16, 4): z = KV quarter. Unnormalized O (bf16) + (m,l f32) partials in qkv scratch.
// LDS = 16K(K) + 16K(V) + 8K(P) = 40960 -> 4 blocks/CU.
__global__ __launch_bounds__(256) void flash6(const BF16* __restrict__ Qb,
                                              const BF16* __restrict__ Kb,
                                              const BF16* __restrict__ VT,
                                              BF16* __restrict__ Opb,
                                              float* __restrict__ ml) {
  const int S = 2560;
  const size_t ZOb = 16ull * 40 * 4096;  // bf16 elements per z-slab
  const size_t ZM = 16ull * 40 * 128;    // f32 per z-slab
  __shared__ BF16 Ks[2][64 * 64];
  __shared__ BF16 Vs[2][64 * 64];
  __shared__ BF16 Ps[4][16 * 64];  // wave-private P, stride 64, XOR-swizzled
  int tid = threadIdx.x, lane = tid & 63, w = tid >> 6;
  int h = blockIdx.y, q0 = blockIdx.x * 64, kz = blockIdx.z;
  int m15 = lane & 15, q4 = lane >> 4;
  int actq = (q0 >= 2048);
  int nt = actq ? ((q0 >> 6) + 1) : 32;
  int tb = (kz * nt) >> 2, te = ((kz + 1) * nt) >> 2;
  const BF16* qrow = Qb + ((size_t)h * S + q0 + w * 16 + m15) * 64;
  bf16x8 qf0 = *(const bf16x8*)(qrow + q4 * 8);
  bf16x8 qf1 = *(const bf16x8*)(qrow + 32 + q4 * 8);
  const BF16* kbase = Kb + (size_t)h * S * 64;
  const BF16* vbase = VT + (size_t)h * 64 * S;
  // staging: 64x64 tile = 512 chunks; 2 per thread
  int L0 = w * 128 + lane, L1 = L0 + 64;
  int r0 = L0 >> 3, c0 = (L0 & 7) ^ (r0 & 7);
  int r1 = L1 >> 3, c1 = (L1 & 7) ^ (r1 & 7);
  {
    const BF16* kg = kbase + (size_t)tb * 64 * 64;
    const BF16* vg = vbase + (size_t)tb * 64;
    async16(kg + (size_t)r0 * 64 + c0 * 8, &Ks[0][L0 * 8]);
    async16(kg + (size_t)r1 * 64 + c1 * 8, &Ks[0][L1 * 8]);
    async16(vg + (size_t)r0 * S + c0 * 8, &Vs[0][L0 * 8]);
    async16(vg + (size_t)r1 * S + c1 * 8, &Vs[0][L1 * 8]);
  }
  f32x4 oa[4] = {};
  float m_i = -1e30f, l_i = 0.f;  // l_i: per-lane partial (reduced at end)
  int colq = q0 + w * 16 + m15;
  char* Pw = (char*)&Ps[w][0];
  int prow = m15 * 128;            // byte offset of this q's P row
  int pswz = (m15 & 7) << 4;       // XOR swizzle (bits 4-6 of row-local byte)
  int x0 = (q4 ^ (m15 & 7)) * 8, x1 = ((4 + q4) ^ (m15 & 7)) * 8;
  __syncthreads();
  for (int t = tb; t < te; t++) {
    int cur = (t - tb) & 1;
    if (t + 1 < te) {
      int nb = cur ^ 1;
      const BF16* kg = kbase + (size_t)(t + 1) * 64 * 64;
      const BF16* vg = vbase + (size_t)(t + 1) * 64;
      async16(kg + (size_t)r0 * 64 + c0 * 8, &Ks[nb][L0 * 8]);
      async16(kg + (size_t)r1 * 64 + c1 * 8, &Ks[nb][L1 * 8]);
      async16(vg + (size_t)r0 * S + c0 * 8, &Vs[nb][L0 * 8]);
      async16(vg + (size_t)r1 * S + c1 * 8, &Vs[nb][L1 * 8]);
    }
    // S^T = K * Q^T (col = q = m15, row = kv)
    f32x4 st[4];
    __builtin_amdgcn_s_setprio(1);
#pragma unroll
    for (int jt = 0; jt < 4; jt++) {
      int row = (jt * 16 + m15) * 64;
      bf16x8 kf0 = *(const bf16x8*)&Ks[cur][row + x0];
      bf16x8 kf1 = *(const bf16x8*)&Ks[cur][row + x1];
      f32x4 zz = {};
      zz = MFMA16(kf0, qf0, zz);
      st[jt] = MFMA16(kf1, qf1, zz);
    }
    __builtin_amdgcn_s_setprio(0);
    float mx = -1e30f;  // per-lane max (covers this lane's 16 scores)
    if (actq && t == nt - 1) {
#pragma unroll
      for (int jt = 0; jt < 4; jt++)
#pragma unroll
        for (int rg = 0; rg < 4; rg++) {
          int rowkv = t * 64 + jt * 16 + q4 * 4 + rg;
          if (rowkv > colq) st[jt][rg] = -1e30f;
          mx = fmaxf(mx, st[jt][rg]);
        }
    } else {
#pragma unroll
      for (int jt = 0; jt < 4; jt++) {
        mx = fmaxf(fmaxf(mx, st[jt][0]), st[jt][1]);  // v_max3
        mx = fmaxf(fmaxf(mx, st[jt][2]), st[jt][3]);
      }
    }
    // defer-max: lane-local check is sufficient (union of lanes covers each row).
    if (!__all(mx <= m_i + 8.f)) {
      float m2 = fmaxf(mx, __shfl_xor(mx, 16));
      m2 = fmaxf(m2, __shfl_xor(m2, 32));
      float mn = fmaxf(m_i, m2);
      float al = exp2f(m_i - mn);
      m_i = mn;
      l_i *= al;
      float alr[4];
#pragma unroll
      for (int rg = 0; rg < 4; rg++) alr[rg] = __shfl(al, q4 * 4 + rg);
#pragma unroll
      for (int dt = 0; dt < 4; dt++)
#pragma unroll
        for (int rg = 0; rg < 4; rg++) oa[dt][rg] *= alr[rg];
    }
    float rs = 0.f;
#pragma unroll
    for (int jt = 0; jt < 4; jt++) {
      float p0 = exp2f(st[jt][0] - m_i), p1 = exp2f(st[jt][1] - m_i);
      float p2 = exp2f(st[jt][2] - m_i), p3 = exp2f(st[jt][3] - m_i);
      rs += (p0 + p1) + (p2 + p3);
      uint2 pr = {pkbf(p0, p1), pkbf(p2, p3)};
      *(uint2*)(Pw + prow + ((jt * 32 + q4 * 8) ^ pswz)) = pr;  // P[q][kv], b64
    }
    l_i += rs;
    // O += P * V  (A = P from wave-private swizzled LDS, B = V^T rows)
    bf16x8 pf0 = *(const bf16x8*)(Pw + prow + ((q4 * 16) ^ pswz));
    bf16x8 pf1 = *(const bf16x8*)(Pw + prow + ((64 + q4 * 16) ^ pswz));
    __builtin_amdgcn_s_setprio(1);
#pragma unroll
    for (int dt = 0; dt < 4; dt++) {
      int vr = (dt * 16 + m15) * 64;
      bf16x8 vf0 = *(const bf16x8*)&Vs[cur][vr + x0];
      bf16x8 vf1 = *(const bf16x8*)&Vs[cur][vr + x1];
      oa[dt] = MFMA16(pf0, vf0, oa[dt]);
      oa[dt] = MFMA16(pf1, vf1, oa[dt]);
    }
    __builtin_amdgcn_s_setprio(0);
    __syncthreads();
  }
  // reduce partial l across the q-group
  l_i += __shfl_xor(l_i, 16);
  l_i += __shfl_xor(l_i, 32);
  if (q4 == 0) {
    float* mp = ml + (size_t)kz * ZM + ((size_t)h * 40 + blockIdx.x) * 128;
    mp[w * 16 + m15] = m_i;
    mp[64 + w * 16 + m15] = l_i;
  }
  // repack partial O f32->bf16 through dead Ks area ([64][72] stride, bank-spread),
  // then coalesced 16B copy-out. Saves half the partial HBM traffic vs f32.
  BF16* rp = &Ks[0][0];  // 64*72*2 = 9216 B <= 16 KB
#pragma unroll
  for (int dt = 0; dt < 4; dt++)
#pragma unroll
    for (int rg = 0; rg < 4; rg++)
      rp[(w * 16 + q4 * 4 + rg) * 72 + dt * 16 + m15] = __float2bfloat16(oa[dt][rg]);
  __syncthreads();
  BF16* Opz = Opb + (size_t)kz * ZOb + ((size_t)h * 40 + blockIdx.x) * 4096;
#pragma unroll
  for (int kk = 0; kk < 2; kk++) {
    int k = tid * 2 + kk;
    int row = k >> 3, ci = k & 7;
    uint4 d = *(const uint4*)&rp[row * 72 + ci * 8];
    *(uint4*)&Opz[(size_t)row * 64 + ci * 8] = d;
  }
}

// ---------------- merge the four KV-quarter bf16 partials -> Obf bf16 ----------------
__global__ __launch_bounds__(256) void fcomb4b(const BF16* __restrict__ Opb,
                                               const float* __restrict__ ml,
                                               BF16* __restrict__ O) {
  int qt = blockIdx.x, h = blockIdx.y;
  int q = threadIdx.x >> 2;          // 0..63
  int d0 = (threadIdx.x & 3) * 16;   // 16 elements per thread
  const size_t ZOb = 16ull * 40 * 4096;
  const size_t ZM = 16ull * 40 * 128;
  size_t tile = (size_t)h * 40 + qt;
  size_t base = tile * 4096 + (size_t)q * 64 + d0;
  size_t mb = tile * 128 + q;
  float m[4], lv[4];
#pragma unroll
  for (int z = 0; z < 4; z++) {
    m[z] = ml[z * ZM + mb];
    lv[z] = ml[z * ZM + mb + 64];
  }
  float M = fmaxf(fmaxf(m[0], m[1]), fmaxf(m[2], m[3]));
  float wz[4];
  float den = 0.f;
#pragma unroll
  for (int z = 0; z < 4; z++) {
    wz[z] = exp2f(m[z] - M);
    den += wz[z] * lv[z];
  }
  float r = 1.f / den;
#pragma unroll
  for (int z = 0; z < 4; z++) wz[z] *= r;
  float acc[16] = {};
#pragma unroll
  for (int z = 0; z < 4; z++) {
    const BF16* P = Opb + z * ZOb + base;
    bf16x8 a = *(const bf16x8*)P;
    bf16x8 b = *(const bf16x8*)(P + 8);
#pragma unroll
    for (int i = 0; i < 8; i++) {
      acc[i] += wz[z] * bf2f(a[i]);
      acc[8 + i] += wz[z] * bf2f(b[i]);
    }
  }
  BF16* orow = O + (size_t)(qt * 64 + q) * 1024 + h * 64 + d0;
  u32 pk[8];
#pragma unroll
  for (int i = 0; i < 8; i++) pk[i] = pkbf(acc[2 * i], acc[2 * i + 1]);
  *(uint4*)&orow[0] = *(uint4*)&pk[0];
  *(uint4*)&orow[8] = *(uint4*)&pk[4];
}

// ---------------- host ----------------
extern "C" void kernel_launch(void* const* d_in, const int* in_sizes, int n_in,
                              void* d_out, int out_size, void* d_ws, size_t ws_size,
                              hipStream_t stream) {
  (void)in_sizes; (void)n_in; (void)out_size; (void)ws_size;
  const float* vid  = (const float*)d_in[0];
  const float* act  = (const float*)d_in[1];
  const float* vfr  = (const float*)d_in[2];
  const float* afr  = (const float*)d_in[3];
  const float* tmv  = (const float*)d_in[4];
  const float* tma  = (const float*)d_in[5];
  const float* Wq   = (const float*)d_in[6];
  const float* Wk   = (const float*)d_in[7];
  const float* Wv   = (const float*)d_in[8];
  const float* Wo   = (const float*)d_in[9];
  const float* bq   = (const float*)d_in[10];
  const float* bk   = (const float*)d_in[11];
  const float* bv   = (const float*)d_in[12];
  const float* bo   = (const float*)d_in[13];
  const float* gq   = (const float*)d_in[14];
  const float* gk   = (const float*)d_in[15];
  const float* modp = (const float*)d_in[16];
  const float* W1   = (const float*)d_in[17];
  const float* b1   = (const float*)d_in[18];
  const float* W2   = (const float*)d_in[19];
  const float* b2   = (const float*)d_in[20];

  char* p = (char*)d_ws;
  auto carve = [&](size_t bytes) {
    char* r = p;
    p += (bytes + 255) & ~(size_t)255;
    return r;
  };
  BF16* WqkvT = (BF16*)carve(4ull * 3072 * 1024 * 2);
  BF16* WoT   = (BF16*)carve(4ull * 1024 * 1024 * 2);
  BF16* W1T   = (BF16*)carve(4ull * 4096 * 1024 * 2);
  BF16* W2T   = (BF16*)carve(4ull * 1024 * 4096 * 2);
  float* bqkv = (float*)carve(4ull * 3072 * 4);
  float* x    = (float*)carve(2560ull * 1024 * 4);
  BF16* abf   = (BF16*)carve(2560ull * 1024 * 2);
  float* qkv  = (float*)carve(2560ull * 3072 * 4);
  BF16* Qb    = (BF16*)carve(2560ull * 1024 * 2);
  BF16* Kb    = (BF16*)carve(2560ull * 1024 * 2);
  float* part = qkv;  // GEMM split-K partials alias qkv(+Qb/Kb for KS=4; dead then)
  const size_t ZOb = 16ull * 40 * 4096;
  BF16* Opb = (BF16*)qkv;                            // flash bf16 partials: 4 x 5.24MB
  float* mlb = (float*)((char*)qkv + 4ull * ZOb * 2);  // + 1.3MB, inside qkv region
  BF16* VTb   = (BF16*)carve(2560ull * 1024 * 2);
  BF16* Obf   = (BF16*)carve(2560ull * 1024 * 2);
  BF16* mibf  = (BF16*)carve(2560ull * 1024 * 2);
  BF16* hbf   = (BF16*)carve(2560ull * 4096 * 2);

  const size_t S3 = 3072ull * 1024;
  wtransq<<<dim3(32, 32, 12), 256, 0, stream>>>(Wq, Wk, Wv, WqkvT);
  wtrans<<<dim3(32, 32, 4), 256, 0, stream>>>(Wo, WoT, 1024, 1024, 1024ull * 1024);
  wtrans<<<dim3(128, 32, 4), 256, 0, stream>>>(W1, W1T, 1024, 4096, 4096ull * 1024);
  wtrans<<<dim3(32, 128, 4), 256, 0, stream>>>(W2, W2T, 4096, 1024, 1024ull * 4096);
  packb<<<48, 256, 0, stream>>>(bq, bk, bv, bqkv);

  // layer-0 first LN reads the original inputs directly (x materialized by combine_ln)
  ln_mod<<<2560, 256, 0, stream>>>(vid, act, abf, modp, tmv, tma, 0, 0, 1);

  for (int l = 0; l < 2; l++) {
    gemm2<0, 1><<<dim3(20, 24, 1), 256, 0, stream>>>(
        abf, WqkvT + (size_t)l * S3, 2 * S3, bqkv + l * 3072, 6144, qkv, nullptr, 3072, 1024);
    qk_post<<<dim3(2560, 2), 256, 0, stream>>>(qkv, gq, gk, Qb, Kb, vfr, afr, l);
    vpost<<<dim3(80, 32), 256, 0, stream>>>(qkv, VTb);
    flash6<<<dim3(40, 16, 4), 256, 0, stream>>>(Qb, Kb, VTb, Opb, mlb);
    fcomb4b<<<dim3(40, 16), 256, 0, stream>>>(Opb, mlb, Obf);
    gemm2<3, 2><<<dim3(20, 8, 2), 256, 0, stream>>>(
        Obf, WoT + (size_t)l * 1024 * 1024, 2ull * 1024 * 1024, nullptr, 0, nullptr, part,
        1024, 1024);
    // residual + gate, then fused LN for the MLP input
    combine_ln<2, 1><<<2560, 256, 0, stream>>>(
        part, bo + l * 1024, modp, 2, l, l, 3, 4, tmv, tma,
        (l == 0) ? vid : x, (l == 0) ? act : (x + 2048ull * 1024), x, mibf);
    gemm2<1, 1><<<dim3(20, 32, 1), 256, 0, stream>>>(
        mibf, W1T + (size_t)l * 4096 * 1024, 2ull * 4096 * 1024, b1 + l * 4096, 8192, hbf,
        nullptr, 4096, 1024);
    gemm2<3, 4><<<dim3(20, 8, 4), 256, 0, stream>>>(
        hbf, W2T + (size_t)l * 4096 * 1024, 2ull * 4096 * 1024, nullptr, 0, nullptr, part,
        1024, 4096);
    if (l == 0) {
      // residual + gate, then fused LN1 of layer 1
      combine_ln<4, 1><<<2560, 256, 0, stream>>>(
          part, b2, modp, 5, 0, 1, 0, 1, tmv, tma, x, x + 2048ull * 1024, x, abf);
    } else {
      combine_ln<4, 0><<<2560, 256, 0, stream>>>(
          part, b2 + 1024, modp, 5, 1, 0, 0, 0, tmv, tma, x, x + 2048ull * 1024,
          (float*)d_out, nullptr);
    }
  }
}

// Round 4
// 741.715 us; speedup vs baseline: 1.0340x; 1.0123x over previous
//
#include <hip/hip_runtime.h>
#include <hip/hip_bf16.h>

#define BF16 __hip_bfloat16
typedef short bf16x8 __attribute__((ext_vector_type(8)));
typedef float f32x4  __attribute__((ext_vector_type(4)));
typedef unsigned int u32;

#define MFMA16(a, b, c) __builtin_amdgcn_mfma_f32_16x16x32_bf16(a, b, c, 0, 0, 0)

// B=1, SV=2048, SA=512, S=2560, D=1024, H=16, DH=64, F=4096, L=2

__device__ __forceinline__ void async16(const void* g, void* l) {
  __builtin_amdgcn_global_load_lds(
      (const __attribute__((address_space(1))) u32*)g,
      (__attribute__((address_space(3))) u32*)l, 16, 0, 0);
}

__device__ __forceinline__ u32 pkbf(float a, float b) {
  union { BF16 h; unsigned short s; } ua, ub;
  ua.h = __float2bfloat16(a); ub.h = __float2bfloat16(b);
  return (u32)ua.s | ((u32)ub.s << 16);
}

__device__ __forceinline__ float bf2f(short s) {
  union { float f; u32 u; } v;
  v.u = ((u32)(unsigned short)s) << 16;
  return v.f;
}

// ---------------- weight transpose + f32->bf16 cast ----------------
__global__ __launch_bounds__(256) void wtrans(const float* __restrict__ W,
                                              BF16* __restrict__ WT, int K, int N,
                                              size_t outZ) {
  __shared__ float t[32][33];
  const float* Wm = W + (size_t)K * N * blockIdx.z;
  BF16* Tm = WT + outZ * blockIdx.z;
  int n0 = blockIdx.x * 32, k0 = blockIdx.y * 32;
  int tx = threadIdx.x & 31, ty = threadIdx.x >> 5;
#pragma unroll
  for (int i = 0; i < 4; i++)
    t[ty + 8 * i][tx] = Wm[(size_t)(k0 + ty + 8 * i) * N + n0 + tx];
  __syncthreads();
#pragma unroll
  for (int i = 0; i < 4; i++)
    Tm[(size_t)(n0 + ty + 8 * i) * K + k0 + tx] = __float2bfloat16(t[tx][ty + 8 * i]);
}

// merged Wq/Wk/Wv transpose: z in [0,12): mat = z>>2, expert = z&3
__global__ __launch_bounds__(256) void wtransq(const float* __restrict__ Wq,
                                               const float* __restrict__ Wk,
                                               const float* __restrict__ Wv,
                                               BF16* __restrict__ WT) {
  __shared__ float t[32][33];
  int mat = blockIdx.z >> 2, ex = blockIdx.z & 3;
  const float* Wm = (mat == 0 ? Wq : mat == 1 ? Wk : Wv) + (size_t)ex * 1024 * 1024;
  BF16* Tm = WT + (size_t)ex * 3072 * 1024 + (size_t)mat * 1024 * 1024;
  int n0 = blockIdx.x * 32, k0 = blockIdx.y * 32;
  int tx = threadIdx.x & 31, ty = threadIdx.x >> 5;
#pragma unroll
  for (int i = 0; i < 4; i++)
    t[ty + 8 * i][tx] = Wm[(size_t)(k0 + ty + 8 * i) * 1024 + n0 + tx];
  __syncthreads();
#pragma unroll
  for (int i = 0; i < 4; i++)
    Tm[(size_t)(n0 + ty + 8 * i) * 1024 + k0 + tx] = __float2bfloat16(t[tx][ty + 8 * i]);
}

// ---------------- fused qkv bias pack ----------------
__global__ __launch_bounds__(256) void packb(const float* __restrict__ bq,
                                             const float* __restrict__ bk,
                                             const float* __restrict__ bv,
                                             float* __restrict__ bqkv) {
  int i = blockIdx.x * 256 + threadIdx.x;  // 4*3072
  int s = i / 3072, c = i - s * 3072;
  float v = (c < 1024) ? bq[s * 1024 + c]
          : (c < 2048) ? bk[s * 1024 + c - 1024]
                       : bv[s * 1024 + c - 2048];
  bqkv[i] = v;
}

// ---------------- LayerNorm * (1+sc) + sh -> bf16 (row-split input) ----------------
__global__ __launch_bounds__(256) void ln_mod(const float* __restrict__ xV,
                                              const float* __restrict__ xA,
                                              BF16* __restrict__ out,
                                              const float* __restrict__ mod,
                                              const float* __restrict__ tmv,
                                              const float* __restrict__ tma,
                                              int l, int ish, int isc) {
  int r = blockIdx.x;
  int e = (r >= 2048) ? 1 : 0;
  const float* xrow = e ? (xA + (size_t)(r - 2048) * 1024) : (xV + (size_t)r * 1024);
  const float* tm = e ? tma : tmv;
  const float* mo = mod + (size_t)((e * 2 + l) * 6) * 1024;
  float4 v = ((const float4*)xrow)[threadIdx.x];
  float s = v.x + v.y + v.z + v.w;
  float s2 = v.x * v.x + v.y * v.y + v.z * v.z + v.w * v.w;
#pragma unroll
  for (int off = 32; off >= 1; off >>= 1) {
    s += __shfl_down(s, off);
    s2 += __shfl_down(s2, off);
  }
  __shared__ float red[8];
  int lane = threadIdx.x & 63, w = threadIdx.x >> 6;
  if (lane == 0) { red[w] = s; red[4 + w] = s2; }
  __syncthreads();
  s = red[0] + red[1] + red[2] + red[3];
  s2 = red[4] + red[5] + red[6] + red[7];
  float mu = s * (1.f / 1024.f);
  float var = s2 * (1.f / 1024.f) - mu * mu;
  float inv = rsqrtf(var + 1e-6f);
  int c = threadIdx.x * 4;
  BF16* o = out + (size_t)r * 1024 + c;
  float xv[4] = {v.x, v.y, v.z, v.w};
#pragma unroll
  for (int k = 0; k < 4; k++) {
    float sc = mo[isc * 1024 + c + k] + tm[isc * 1024 + c + k];
    float sh = mo[ish * 1024 + c + k] + tm[ish * 1024 + c + k];
    o[k] = __float2bfloat16((xv[k] - mu) * inv * (1.f + sc) + sh);
  }
}

// ---------------- RMSNorm + gain + RoPE, reads fused qkv (stride 3072) ----------------
// Q rows are pre-scaled by 0.125*log2(e) so flash uses exp2 with raw dot products.
__global__ __launch_bounds__(256) void qk_post(const float* __restrict__ qkv,
                                               const float* __restrict__ gq,
                                               const float* __restrict__ gk,
                                               BF16* __restrict__ Qb, BF16* __restrict__ Kb,
                                               const float* __restrict__ vfreq,
                                               const float* __restrict__ afreq, int l) {
  int r = blockIdx.x;
  int which = blockIdx.y;
  const float* src = qkv + (size_t)r * 3072 + which * 1024;
  int e = (r >= 2048) ? 1 : 0;
  const float* g = (which ? gk : gq) + (size_t)(e * 2 + l) * 1024;
  BF16* dst = which ? Kb : Qb;
  const float* fr = e ? (afreq + (size_t)(r - 2048) * 32) : (vfreq + (size_t)r * 32);
  float4 v = ((const float4*)src)[threadIdx.x];
  float s2 = v.x * v.x + v.y * v.y + v.z * v.z + v.w * v.w;
#pragma unroll
  for (int off = 32; off >= 1; off >>= 1) s2 += __shfl_down(s2, off);
  __shared__ float red[4];
  int lane = threadIdx.x & 63, w = threadIdx.x >> 6;
  if (lane == 0) red[w] = s2;
  __syncthreads();
  s2 = red[0] + red[1] + red[2] + red[3];
  float inv = rsqrtf(s2 * (1.f / 1024.f) + 1e-6f);
  if (which == 0) inv *= 0.125f * 1.44269504f;  // fold softmax scale into Q
  int c = threadIdx.x * 4;
  float xe0 = v.x * inv * g[c], xo0 = v.y * inv * g[c + 1];
  float xe1 = v.z * inv * g[c + 2], xo1 = v.w * inv * g[c + 3];
  int p0 = (c & 63) >> 1;
  float c0, s0, c1, s1;
  __sincosf(fr[p0], &s0, &c0);
  __sincosf(fr[p0 + 1], &s1, &c1);
  int h = c >> 6;
  size_t o = ((size_t)h * 2560 + r) * 64 + (c & 63);
  dst[o + 0] = __float2bfloat16(xe0 * c0 - xo0 * s0);
  dst[o + 1] = __float2bfloat16(xe0 * s0 + xo0 * c0);
  dst[o + 2] = __float2bfloat16(xe1 * c1 - xo1 * s1);
  dst[o + 3] = __float2bfloat16(xe1 * s1 + xo1 * c1);
}

// ---------------- V (from qkv col 2048, stride 3072) -> V^T (H*DH, S) bf16 ----------------
__global__ __launch_bounds__(256) void vpost(const float* __restrict__ qkv,
                                             BF16* __restrict__ VT) {
  __shared__ float t[32][33];
  int r0 = blockIdx.x * 32, c0 = blockIdx.y * 32;
  int tx = threadIdx.x & 31, ty = threadIdx.x >> 5;
#pragma unroll
  for (int i = 0; i < 4; i++)
    t[ty + 8 * i][tx] = qkv[(size_t)(r0 + ty + 8 * i) * 3072 + 2048 + c0 + tx];
  __syncthreads();
#pragma unroll
  for (int i = 0; i < 4; i++)
    VT[(size_t)(c0 + ty + 8 * i) * 2560 + r0 + tx] = __float2bfloat16(t[tx][ty + 8 * i]);
}

// ---------------- GEMM v3: double-buffered LDS, prefetch-overlapped K-loop ----------------
// C = A(2560xK) * B^T(NxK), expert-aware, BK=64, one barrier per K-step.
// EPI: 0 = f32 out +bias, 1 = gelu->bf16 +bias, 3 = bf16 split-K partials (no bias)
template <int EPI, int KS>
__global__ __launch_bounds__(256) void gemm2(const BF16* __restrict__ A,
                                             const BF16* __restrict__ Bw, size_t Bestride,
                                             const float* __restrict__ bias, int biasE,
                                             void* __restrict__ out, BF16* __restrict__ part,
                                             int N, int K) {
  __shared__ BF16 As[2][128 * 64];
  __shared__ BF16 Bs[2][128 * 64];
  int flat = blockIdx.x + blockIdx.y * gridDim.x;
  int xcd = flat & 7, slot = flat >> 3;
  int bx = slot % gridDim.x;
  int by = (slot / gridDim.x) * 8 + xcd;
  int m0 = bx * 128, n0 = by * 128;
  int e = (m0 >= 2048);
  const BF16* Ab = A + (size_t)m0 * K;
  const BF16* Bb = Bw + (e ? Bestride : 0) + (size_t)n0 * K;
  int kz0 = blockIdx.z * (K / KS);
  int nk = (K / KS) >> 6;
  int tid = threadIdx.x, lane = tid & 63, w = tid >> 6;
  int wr = w & 1, wc = w >> 1;
  int m15 = lane & 15, q4 = lane >> 4;
  int L[4], rS[4], cS[4];
#pragma unroll
  for (int i = 0; i < 4; i++) {
    L[i] = w * 256 + i * 64 + lane;
    rS[i] = L[i] >> 3;
    cS[i] = (L[i] & 7) ^ (rS[i] & 7);
  }
  f32x4 acc[4][4] = {};
  // prologue: stage tile 0 into buffer 0
#pragma unroll
  for (int i = 0; i < 4; i++) {
    async16(Ab + (size_t)rS[i] * K + kz0 + cS[i] * 8, &As[0][L[i] * 8]);
    async16(Bb + (size_t)rS[i] * K + kz0 + cS[i] * 8, &Bs[0][L[i] * 8]);
  }
  __syncthreads();  // drains prologue loads
  for (int t = 0; t < nk; t++) {
    int cur = t & 1, nb = cur ^ 1;
    if (t + 1 < nk) {  // issue next-tile loads; they fly under this tile's MFMA
      int k0 = kz0 + (t + 1) * 64;
#pragma unroll
      for (int i = 0; i < 4; i++) {
        async16(Ab + (size_t)rS[i] * K + k0 + cS[i] * 8, &As[nb][L[i] * 8]);
        async16(Bb + (size_t)rS[i] * K + k0 + cS[i] * 8, &Bs[nb][L[i] * 8]);
      }
    }
#pragma unroll
    for (int kk = 0; kk < 2; kk++) {
      int pos = ((kk * 4 + q4) ^ (m15 & 7)) * 8;
      bf16x8 af[4], bv[4];
#pragma unroll
      for (int i = 0; i < 4; i++)
        af[i] = *(const bf16x8*)&As[cur][(wr * 64 + i * 16 + m15) * 64 + pos];
#pragma unroll
      for (int j = 0; j < 4; j++)
        bv[j] = *(const bf16x8*)&Bs[cur][(wc * 64 + j * 16 + m15) * 64 + pos];
#pragma unroll
      for (int i = 0; i < 4; i++)
#pragma unroll
        for (int j = 0; j < 4; j++)
          acc[i][j] = MFMA16(af[i], bv[j], acc[i][j]);
    }
    __syncthreads();  // next-tile loads (mostly landed) + read-done fence
  }
#pragma unroll
  for (int i = 0; i < 4; i++) {
    int row = m0 + wr * 64 + 16 * i + q4 * 4;
#pragma unroll
    for (int j = 0; j < 4; j++) {
      int col = n0 + wc * 64 + 16 * j + m15;
      float b = (EPI == 3) ? 0.f : bias[e * biasE + col];
#pragma unroll
      for (int rg = 0; rg < 4; rg++) {
        float v = acc[i][j][rg] + b;
        size_t idx = (size_t)(row + rg) * N + col;
        if (EPI == 0) {
          ((float*)out)[idx] = v;
        } else if (EPI == 1) {
          // gelu(tanh) == v / (1 + exp2(-2*log2e*u)); exact at +-inf, monotone
          float u = v * (0.7978845608f + 0.0356774081f * v * v);
          float d = 1.f + exp2f(-2.8853900818f * u);
          ((BF16*)out)[idx] = __float2bfloat16(v * __builtin_amdgcn_rcpf(d));
        } else {
          part[(size_t)blockIdx.z * 2560 * N + idx] = __float2bfloat16(v);
        }
      }
    }
  }
}

// ---------------- split-K combine (bf16 partials) + gated residual (+ fused LN) ----------------
template <int KS, int LN>
__global__ __launch_bounds__(256) void combine_ln(const BF16* __restrict__ part,
                                                  const float* __restrict__ biasL,
                                                  const float* __restrict__ modp,
                                                  int gi, int lg, int ll, int ish, int isc,
                                                  const float* __restrict__ tmv,
                                                  const float* __restrict__ tma,
                                                  const float* __restrict__ xinV,
                                                  const float* __restrict__ xinA,
                                                  float* __restrict__ xout,
                                                  BF16* __restrict__ lnout) {
  int r = blockIdx.x, e = (r >= 2048) ? 1 : 0;
  int c = threadIdx.x * 4;
  float4 s = {0.f, 0.f, 0.f, 0.f};
#pragma unroll
  for (int z = 0; z < KS; z++) {
    short4 p4 = *(const short4*)&part[((size_t)z * 2560 + r) * 1024 + c];
    s.x += bf2f(p4.x); s.y += bf2f(p4.y); s.z += bf2f(p4.z); s.w += bf2f(p4.w);
  }
  float4 b = *(const float4*)&biasL[e * 2048 + c];
  const float* tm = e ? tma : tmv;
  float4 gm = *(const float4*)&modp[(size_t)((e * 2 + lg) * 6 + gi) * 1024 + c];
  float4 gt = *(const float4*)&tm[gi * 1024 + c];
  const float* xrow = e ? (xinA + (size_t)(r - 2048) * 1024) : (xinV + (size_t)r * 1024);
  float4 xi = *(const float4*)&xrow[c];
  float4 o;
  o.x = xi.x + (gm.x + gt.x) * (s.x + b.x);
  o.y = xi.y + (gm.y + gt.y) * (s.y + b.y);
  o.z = xi.z + (gm.z + gt.z) * (s.z + b.z);
  o.w = xi.w + (gm.w + gt.w) * (s.w + b.w);
  *(float4*)&xout[(size_t)r * 1024 + c] = o;
  if (LN) {
    float su = o.x + o.y + o.z + o.w;
    float s2 = o.x * o.x + o.y * o.y + o.z * o.z + o.w * o.w;
#pragma unroll
    for (int off = 32; off >= 1; off >>= 1) {
      su += __shfl_down(su, off);
      s2 += __shfl_down(s2, off);
    }
    __shared__ float red[8];
    int lane = threadIdx.x & 63, w = threadIdx.x >> 6;
    if (lane == 0) { red[w] = su; red[4 + w] = s2; }
    __syncthreads();
    su = red[0] + red[1] + red[2] + red[3];
    s2 = red[4] + red[5] + red[6] + red[7];
    float mu = su * (1.f / 1024.f);
    float var = s2 * (1.f / 1024.f) - mu * mu;
    float inv = rsqrtf(var + 1e-6f);
    const float* mo = modp + (size_t)((e * 2 + ll) * 6) * 1024;
    BF16* ob = lnout + (size_t)r * 1024 + c;
    float ov[4] = {o.x, o.y, o.z, o.w};
#pragma unroll
    for (int k = 0; k < 4; k++) {
      float sc = mo[isc * 1024 + c + k] + tm[isc * 1024 + c + k];
      float sh = mo[ish * 1024 + c + k] + tm[ish * 1024 + c + k];
      ob[k] = __float2bfloat16((ov[k] - mu) * inv * (1.f + sc) + sh);
    }
  }
}

// ---------------- flash v6: 4-way KV split, bf16 partials via LDS repack ----------------
// Qb (pre-scaled),Kb: (H,S,DH) bf16; VT: (H,DH,S) bf16
// grid (40, 16, 4): z = KV quarter. Unnormalized O (bf16) + (m,l f32) partials in qkv scratch.
// LDS = 16K(K) + 16K(V) + 8K(P) = 40960 -> 4 blocks/CU.
__global__ __launch_bounds__(256) void flash6(const BF16* __restrict__ Qb,
                                              const BF16* __restrict__ Kb,
                                              const BF16* __restrict__ VT,
                                              BF16* __restrict__ Opb,
                                              float* __restrict__ ml) {
  const int S = 2560;
  const size_t ZOb = 16ull * 40 * 4096;  // bf16 elements per z-slab
  const size_t ZM = 16ull * 40 * 128;    // f32 per z-slab
  __shared__ BF16 Ks[2][64 * 64];
  __shared__ BF16 Vs[2][64 * 64];
  __shared__ BF16 Ps[4][16 * 64];  // wave-private P, stride 64, XOR-swizzled
  int tid = threadIdx.x, lane = tid & 63, w = tid >> 6;
  int h = blockIdx.y, q0 = blockIdx.x * 64, kz = blockIdx.z;
  int m15 = lane & 15, q4 = lane >> 4;
  int actq = (q0 >= 2048);
  int nt = actq ? ((q0 >> 6) + 1) : 32;
  int tb = (kz * nt) >> 2, te = ((kz + 1) * nt) >> 2;
  const BF16* qrow = Qb + ((size_t)h * S + q0 + w * 16 + m15) * 64;
  bf16x8 qf0 = *(const bf16x8*)(qrow + q4 * 8);
  bf16x8 qf1 = *(const bf16x8*)(qrow + 32 + q4 * 8);
  const BF16* kbase = Kb + (size_t)h * S * 64;
  const BF16* vbase = VT + (size_t)h * 64 * S;
  // staging: 64x64 tile = 512 chunks; 2 per thread
  int L0 = w * 128 + lane, L1 = L0 + 64;
  int r0 = L0 >> 3, c0 = (L0 & 7) ^ (r0 & 7);
  int r1 = L1 >> 3, c1 = (L1 & 7) ^ (r1 & 7);
  {
    const BF16* kg = kbase + (size_t)tb * 64 * 64;
    const BF16* vg = vbase + (size_t)tb * 64;
    async16(kg + (size_t)r0 * 64 + c0 * 8, &Ks[0][L0 * 8]);
    async16(kg + (size_t)r1 * 64 + c1 * 8, &Ks[0][L1 * 8]);
    async16(vg + (size_t)r0 * S + c0 * 8, &Vs[0][L0 * 8]);
    async16(vg + (size_t)r1 * S + c1 * 8, &Vs[0][L1 * 8]);
  }
  f32x4 oa[4] = {};
  float m_i = -1e30f, l_i = 0.f;  // l_i: per-lane partial (reduced at end)
  int colq = q0 + w * 16 + m15;
  char* Pw = (char*)&Ps[w][0];
  int prow = m15 * 128;            // byte offset of this q's P row
  int pswz = (m15 & 7) << 4;       // XOR swizzle (bits 4-6 of row-local byte)
  int x0 = (q4 ^ (m15 & 7)) * 8, x1 = ((4 + q4) ^ (m15 & 7)) * 8;
  __syncthreads();
  for (int t = tb; t < te; t++) {
    int cur = (t - tb) & 1;
    if (t + 1 < te) {
      int nb = cur ^ 1;
      const BF16* kg = kbase + (size_t)(t + 1) * 64 * 64;
      const BF16* vg = vbase + (size_t)(t + 1) * 64;
      async16(kg + (size_t)r0 * 64 + c0 * 8, &Ks[nb][L0 * 8]);
      async16(kg + (size_t)r1 * 64 + c1 * 8, &Ks[nb][L1 * 8]);
      async16(vg + (size_t)r0 * S + c0 * 8, &Vs[nb][L0 * 8]);
      async16(vg + (size_t)r1 * S + c1 * 8, &Vs[nb][L1 * 8]);
    }
    // S^T = K * Q^T (col = q = m15, row = kv)
    f32x4 st[4];
    __builtin_amdgcn_s_setprio(1);
#pragma unroll
    for (int jt = 0; jt < 4; jt++) {
      int row = (jt * 16 + m15) * 64;
      bf16x8 kf0 = *(const bf16x8*)&Ks[cur][row + x0];
      bf16x8 kf1 = *(const bf16x8*)&Ks[cur][row + x1];
      f32x4 zz = {};
      zz = MFMA16(kf0, qf0, zz);
      st[jt] = MFMA16(kf1, qf1, zz);
    }
    __builtin_amdgcn_s_setprio(0);
    float mx = -1e30f;  // per-lane max (covers this lane's 16 scores)
    if (actq && t == nt - 1) {
#pragma unroll
      for (int jt = 0; jt < 4; jt++)
#pragma unroll
        for (int rg = 0; rg < 4; rg++) {
          int rowkv = t * 64 + jt * 16 + q4 * 4 + rg;
          if (rowkv > colq) st[jt][rg] = -1e30f;
          mx = fmaxf(mx, st[jt][rg]);
        }
    } else {
#pragma unroll
      for (int jt = 0; jt < 4; jt++) {
        mx = fmaxf(fmaxf(mx, st[jt][0]), st[jt][1]);  // v_max3
        mx = fmaxf(fmaxf(mx, st[jt][2]), st[jt][3]);
      }
    }
    // defer-max: lane-local check is sufficient (union of lanes covers each row).
    if (!__all(mx <= m_i + 8.f)) {
      float m2 = fmaxf(mx, __shfl_xor(mx, 16));
      m2 = fmaxf(m2, __shfl_xor(m2, 32));
      float mn = fmaxf(m_i, m2);
      float al = exp2f(m_i - mn);
      m_i = mn;
      l_i *= al;
      float alr[4];
#pragma unroll
      for (int rg = 0; rg < 4; rg++) alr[rg] = __shfl(al, q4 * 4 + rg);
#pragma unroll
      for (int dt = 0; dt < 4; dt++)
#pragma unroll
        for (int rg = 0; rg < 4; rg++) oa[dt][rg] *= alr[rg];
    }
    float rs = 0.f;
#pragma unroll
    for (int jt = 0; jt < 4; jt++) {
      float p0 = exp2f(st[jt][0] - m_i), p1 = exp2f(st[jt][1] - m_i);
      float p2 = exp2f(st[jt][2] - m_i), p3 = exp2f(st[jt][3] - m_i);
      rs += (p0 + p1) + (p2 + p3);
      uint2 pr = {pkbf(p0, p1), pkbf(p2, p3)};
      *(uint2*)(Pw + prow + ((jt * 32 + q4 * 8) ^ pswz)) = pr;  // P[q][kv], b64
    }
    l_i += rs;
    // O += P * V  (A = P from wave-private swizzled LDS, B = V^T rows)
    bf16x8 pf0 = *(const bf16x8*)(Pw + prow + ((q4 * 16) ^ pswz));
    bf16x8 pf1 = *(const bf16x8*)(Pw + prow + ((64 + q4 * 16) ^ pswz));
    __builtin_amdgcn_s_setprio(1);
#pragma unroll
    for (int dt = 0; dt < 4; dt++) {
      int vr = (dt * 16 + m15) * 64;
      bf16x8 vf0 = *(const bf16x8*)&Vs[cur][vr + x0];
      bf16x8 vf1 = *(const bf16x8*)&Vs[cur][vr + x1];
      oa[dt] = MFMA16(pf0, vf0, oa[dt]);
      oa[dt] = MFMA16(pf1, vf1, oa[dt]);
    }
    __builtin_amdgcn_s_setprio(0);
    __syncthreads();
  }
  // reduce partial l across the q-group
  l_i += __shfl_xor(l_i, 16);
  l_i += __shfl_xor(l_i, 32);
  if (q4 == 0) {
    float* mp = ml + (size_t)kz * ZM + ((size_t)h * 40 + blockIdx.x) * 128;
    mp[w * 16 + m15] = m_i;
    mp[64 + w * 16 + m15] = l_i;
  }
  // repack partial O f32->bf16 through dead Ks area ([64][72] stride, bank-spread),
  // then coalesced 16B copy-out. Saves half the partial HBM traffic vs f32.
  BF16* rp = &Ks[0][0];  // 64*72*2 = 9216 B <= 16 KB
#pragma unroll
  for (int dt = 0; dt < 4; dt++)
#pragma unroll
    for (int rg = 0; rg < 4; rg++)
      rp[(w * 16 + q4 * 4 + rg) * 72 + dt * 16 + m15] = __float2bfloat16(oa[dt][rg]);
  __syncthreads();
  BF16* Opz = Opb + (size_t)kz * ZOb + ((size_t)h * 40 + blockIdx.x) * 4096;
#pragma unroll
  for (int kk = 0; kk < 2; kk++) {
    int k = tid * 2 + kk;
    int row = k >> 3, ci = k & 7;
    uint4 d = *(const uint4*)&rp[row * 72 + ci * 8];
    *(uint4*)&Opz[(size_t)row * 64 + ci * 8] = d;
  }
}

// ---------------- merge the four KV-quarter bf16 partials -> Obf bf16 ----------------
__global__ __launch_bounds__(256) void fcomb4b(const BF16* __restrict__ Opb,
                                               const float* __restrict__ ml,
                                               BF16* __restrict__ O) {
  int qt = blockIdx.x, h = blockIdx.y;
  int q = threadIdx.x >> 2;          // 0..63
  int d0 = (threadIdx.x & 3) * 16;   // 16 elements per thread
  const size_t ZOb = 16ull * 40 * 4096;
  const size_t ZM = 16ull * 40 * 128;
  size_t tile = (size_t)h * 40 + qt;
  size_t base = tile * 4096 + (size_t)q * 64 + d0;
  size_t mb = tile * 128 + q;
  float m[4], lv[4];
#pragma unroll
  for (int z = 0; z < 4; z++) {
    m[z] = ml[z * ZM + mb];
    lv[z] = ml[z * ZM + mb + 64];
  }
  float M = fmaxf(fmaxf(m[0], m[1]), fmaxf(m[2], m[3]));
  float wz[4];
  float den = 0.f;
#pragma unroll
  for (int z = 0; z < 4; z++) {
    wz[z] = exp2f(m[z] - M);
    den += wz[z] * lv[z];
  }
  float r = 1.f / den;
#pragma unroll
  for (int z = 0; z < 4; z++) wz[z] *= r;
  float acc[16] = {};
#pragma unroll
  for (int z = 0; z < 4; z++) {
    const BF16* P = Opb + z * ZOb + base;
    bf16x8 a = *(const bf16x8*)P;
    bf16x8 b = *(const bf16x8*)(P + 8);
#pragma unroll
    for (int i = 0; i < 8; i++) {
      acc[i] += wz[z] * bf2f(a[i]);
      acc[8 + i] += wz[z] * bf2f(b[i]);
    }
  }
  BF16* orow = O + (size_t)(qt * 64 + q) * 1024 + h * 64 + d0;
  u32 pk[8];
#pragma unroll
  for (int i = 0; i < 8; i++) pk[i] = pkbf(acc[2 * i], acc[2 * i + 1]);
  *(uint4*)&orow[0] = *(uint4*)&pk[0];
  *(uint4*)&orow[8] = *(uint4*)&pk[4];
}

// ---------------- host ----------------
extern "C" void kernel_launch(void* const* d_in, const int* in_sizes, int n_in,
                              void* d_out, int out_size, void* d_ws, size_t ws_size,
                              hipStream_t stream) {
  (void)in_sizes; (void)n_in; (void)out_size; (void)ws_size;
  const float* vid  = (const float*)d_in[0];
  const float* act  = (const float*)d_in[1];
  const float* vfr  = (const float*)d_in[2];
  const float* afr  = (const float*)d_in[3];
  const float* tmv  = (const float*)d_in[4];
  const float* tma  = (const float*)d_in[5];
  const float* Wq   = (const float*)d_in[6];
  const float* Wk   = (const float*)d_in[7];
  const float* Wv   = (const float*)d_in[8];
  const float* Wo   = (const float*)d_in[9];
  const float* bq   = (const float*)d_in[10];
  const float* bk   = (const float*)d_in[11];
  const float* bv   = (const float*)d_in[12];
  const float* bo   = (const float*)d_in[13];
  const float* gq   = (const float*)d_in[14];
  const float* gk   = (const float*)d_in[15];
  const float* modp = (const float*)d_in[16];
  const float* W1   = (const float*)d_in[17];
  const float* b1   = (const float*)d_in[18];
  const float* W2   = (const float*)d_in[19];
  const float* b2   = (const float*)d_in[20];

  char* p = (char*)d_ws;
  auto carve = [&](size_t bytes) {
    char* r = p;
    p += (bytes + 255) & ~(size_t)255;
    return r;
  };
  BF16* WqkvT = (BF16*)carve(4ull * 3072 * 1024 * 2);
  BF16* WoT   = (BF16*)carve(4ull * 1024 * 1024 * 2);
  BF16* W1T   = (BF16*)carve(4ull * 4096 * 1024 * 2);
  BF16* W2T   = (BF16*)carve(4ull * 1024 * 4096 * 2);
  float* bqkv = (float*)carve(4ull * 3072 * 4);
  float* x    = (float*)carve(2560ull * 1024 * 4);
  BF16* abf   = (BF16*)carve(2560ull * 1024 * 2);
  float* qkv  = (float*)carve(2560ull * 3072 * 4);
  BF16* Qb    = (BF16*)carve(2560ull * 1024 * 2);
  BF16* Kb    = (BF16*)carve(2560ull * 1024 * 2);
  BF16* part = (BF16*)qkv;  // GEMM split-K bf16 partials alias qkv (dead then)
  const size_t ZOb = 16ull * 40 * 4096;
  BF16* Opb = (BF16*)qkv;                              // flash bf16 partials: 4 x 5.24MB
  float* mlb = (float*)((char*)qkv + 4ull * ZOb * 2);  // + 1.3MB, inside qkv region
  BF16* VTb   = (BF16*)carve(2560ull * 1024 * 2);
  BF16* Obf   = (BF16*)carve(2560ull * 1024 * 2);
  BF16* mibf  = (BF16*)carve(2560ull * 1024 * 2);
  BF16* hbf   = (BF16*)carve(2560ull * 4096 * 2);

  const size_t S3 = 3072ull * 1024;
  wtransq<<<dim3(32, 32, 12), 256, 0, stream>>>(Wq, Wk, Wv, WqkvT);
  wtrans<<<dim3(32, 32, 4), 256, 0, stream>>>(Wo, WoT, 1024, 1024, 1024ull * 1024);
  wtrans<<<dim3(128, 32, 4), 256, 0, stream>>>(W1, W1T, 1024, 4096, 4096ull * 1024);
  wtrans<<<dim3(32, 128, 4), 256, 0, stream>>>(W2, W2T, 4096, 1024, 1024ull * 4096);
  packb<<<48, 256, 0, stream>>>(bq, bk, bv, bqkv);

  // layer-0 first LN reads the original inputs directly (x materialized by combine_ln)
  ln_mod<<<2560, 256, 0, stream>>>(vid, act, abf, modp, tmv, tma, 0, 0, 1);

  for (int l = 0; l < 2; l++) {
    gemm2<0, 1><<<dim3(20, 24, 1), 256, 0, stream>>>(
        abf, WqkvT + (size_t)l * S3, 2 * S3, bqkv + l * 3072, 6144, qkv, nullptr, 3072, 1024);
    qk_post<<<dim3(2560, 2), 256, 0, stream>>>(qkv, gq, gk, Qb, Kb, vfr, afr, l);
    vpost<<<dim3(80, 32), 256, 0, stream>>>(qkv, VTb);
    flash6<<<dim3(40, 16, 4), 256, 0, stream>>>(Qb, Kb, VTb, Opb, mlb);
    fcomb4b<<<dim3(40, 16), 256, 0, stream>>>(Opb, mlb, Obf);
    gemm2<3, 2><<<dim3(20, 8, 2), 256, 0, stream>>>(
        Obf, WoT + (size_t)l * 1024 * 1024, 2ull * 1024 * 1024, nullptr, 0, nullptr, part,
        1024, 1024);
    // residual + gate, then fused LN for the MLP input
    combine_ln<2, 1><<<2560, 256, 0, stream>>>(
        part, bo + l * 1024, modp, 2, l, l, 3, 4, tmv, tma,
        (l == 0) ? vid : x, (l == 0) ? act : (x + 2048ull * 1024), x, mibf);
    gemm2<1, 1><<<dim3(20, 32, 1), 256, 0, stream>>>(
        mibf, W1T + (size_t)l * 4096 * 1024, 2ull * 4096 * 1024, b1 + l * 4096, 8192, hbf,
        nullptr, 4096, 1024);
    gemm2<3, 4><<<dim3(20, 8, 4), 256, 0, stream>>>(
        hbf, W2T + (size_t)l * 4096 * 1024, 2ull * 4096 * 1024, nullptr, 0, nullptr, part,
        1024, 4096);
    if (l == 0) {
      // residual + gate, then fused LN1 of layer 1
      combine_ln<4, 1><<<2560, 256, 0, stream>>>(
          part, b2, modp, 5, 0, 1, 0, 1, tmv, tma, x, x + 2048ull * 1024, x, abf);
    } else {
      combine_ln<4, 0><<<2560, 256, 0, stream>>>(
          part, b2 + 1024, modp, 5, 1, 0, 0, 0, tmv, tma, x, x + 2048ull * 1024,
          (float*)d_out, nullptr);
    }
  }
}

// Round 5
// 718.408 us; speedup vs baseline: 1.0675x; 1.0324x over previous
//
#include <hip/hip_runtime.h>
#include <hip/hip_bf16.h>

#define BF16 __hip_bfloat16
typedef short bf16x8 __attribute__((ext_vector_type(8)));
typedef float f32x4  __attribute__((ext_vector_type(4)));
typedef unsigned int u32;

#define MFMA16(a, b, c) __builtin_amdgcn_mfma_f32_16x16x32_bf16(a, b, c, 0, 0, 0)

// B=1, SV=2048, SA=512, S=2560, D=1024, H=16, DH=64, F=4096, L=2

__device__ __forceinline__ void async16(const void* g, void* l) {
  __builtin_amdgcn_global_load_lds(
      (const __attribute__((address_space(1))) u32*)g,
      (__attribute__((address_space(3))) u32*)l, 16, 0, 0);
}

__device__ __forceinline__ u32 pkbf(float a, float b) {
  union { BF16 h; unsigned short s; } ua, ub;
  ua.h = __float2bfloat16(a); ub.h = __float2bfloat16(b);
  return (u32)ua.s | ((u32)ub.s << 16);
}

__device__ __forceinline__ float bf2f(short s) {
  union { float f; u32 u; } v;
  v.u = ((u32)(unsigned short)s) << 16;
  return v.f;
}

// ---------------- weight transpose + f32->bf16 cast ----------------
__global__ __launch_bounds__(256) void wtrans(const float* __restrict__ W,
                                              BF16* __restrict__ WT, int K, int N,
                                              size_t outZ) {
  __shared__ float t[32][33];
  const float* Wm = W + (size_t)K * N * blockIdx.z;
  BF16* Tm = WT + outZ * blockIdx.z;
  int n0 = blockIdx.x * 32, k0 = blockIdx.y * 32;
  int tx = threadIdx.x & 31, ty = threadIdx.x >> 5;
#pragma unroll
  for (int i = 0; i < 4; i++)
    t[ty + 8 * i][tx] = Wm[(size_t)(k0 + ty + 8 * i) * N + n0 + tx];
  __syncthreads();
#pragma unroll
  for (int i = 0; i < 4; i++)
    Tm[(size_t)(n0 + ty + 8 * i) * K + k0 + tx] = __float2bfloat16(t[tx][ty + 8 * i]);
}

// merged Wq/Wk/Wv transpose: z in [0,12): mat = z>>2, expert = z&3
__global__ __launch_bounds__(256) void wtransq(const float* __restrict__ Wq,
                                               const float* __restrict__ Wk,
                                               const float* __restrict__ Wv,
                                               BF16* __restrict__ WT) {
  __shared__ float t[32][33];
  int mat = blockIdx.z >> 2, ex = blockIdx.z & 3;
  const float* Wm = (mat == 0 ? Wq : mat == 1 ? Wk : Wv) + (size_t)ex * 1024 * 1024;
  BF16* Tm = WT + (size_t)ex * 3072 * 1024 + (size_t)mat * 1024 * 1024;
  int n0 = blockIdx.x * 32, k0 = blockIdx.y * 32;
  int tx = threadIdx.x & 31, ty = threadIdx.x >> 5;
#pragma unroll
  for (int i = 0; i < 4; i++)
    t[ty + 8 * i][tx] = Wm[(size_t)(k0 + ty + 8 * i) * 1024 + n0 + tx];
  __syncthreads();
#pragma unroll
  for (int i = 0; i < 4; i++)
    Tm[(size_t)(n0 + ty + 8 * i) * 1024 + k0 + tx] = __float2bfloat16(t[tx][ty + 8 * i]);
}

// ---------------- fused qkv bias pack ----------------
__global__ __launch_bounds__(256) void packb(const float* __restrict__ bq,
                                             const float* __restrict__ bk,
                                             const float* __restrict__ bv,
                                             float* __restrict__ bqkv) {
  int i = blockIdx.x * 256 + threadIdx.x;  // 4*3072
  int s = i / 3072, c = i - s * 3072;
  float v = (c < 1024) ? bq[s * 1024 + c]
          : (c < 2048) ? bk[s * 1024 + c - 1024]
                       : bv[s * 1024 + c - 2048];
  bqkv[i] = v;
}

// ---------------- LayerNorm * (1+sc) + sh -> bf16 (row-split input) ----------------
__global__ __launch_bounds__(256) void ln_mod(const float* __restrict__ xV,
                                              const float* __restrict__ xA,
                                              BF16* __restrict__ out,
                                              const float* __restrict__ mod,
                                              const float* __restrict__ tmv,
                                              const float* __restrict__ tma,
                                              int l, int ish, int isc) {
  int r = blockIdx.x;
  int e = (r >= 2048) ? 1 : 0;
  const float* xrow = e ? (xA + (size_t)(r - 2048) * 1024) : (xV + (size_t)r * 1024);
  const float* tm = e ? tma : tmv;
  const float* mo = mod + (size_t)((e * 2 + l) * 6) * 1024;
  float4 v = ((const float4*)xrow)[threadIdx.x];
  float s = v.x + v.y + v.z + v.w;
  float s2 = v.x * v.x + v.y * v.y + v.z * v.z + v.w * v.w;
#pragma unroll
  for (int off = 32; off >= 1; off >>= 1) {
    s += __shfl_down(s, off);
    s2 += __shfl_down(s2, off);
  }
  __shared__ float red[8];
  int lane = threadIdx.x & 63, w = threadIdx.x >> 6;
  if (lane == 0) { red[w] = s; red[4 + w] = s2; }
  __syncthreads();
  s = red[0] + red[1] + red[2] + red[3];
  s2 = red[4] + red[5] + red[6] + red[7];
  float mu = s * (1.f / 1024.f);
  float var = s2 * (1.f / 1024.f) - mu * mu;
  float inv = rsqrtf(var + 1e-6f);
  int c = threadIdx.x * 4;
  BF16* o = out + (size_t)r * 1024 + c;
  float xv[4] = {v.x, v.y, v.z, v.w};
#pragma unroll
  for (int k = 0; k < 4; k++) {
    float sc = mo[isc * 1024 + c + k] + tm[isc * 1024 + c + k];
    float sh = mo[ish * 1024 + c + k] + tm[ish * 1024 + c + k];
    o[k] = __float2bfloat16((xv[k] - mu) * inv * (1.f + sc) + sh);
  }
}

// ---------------- RMSNorm + gain + RoPE, reads fused qkv (stride 3072) ----------------
// Q rows are pre-scaled by 0.125*log2(e) so flash uses exp2 with raw dot products.
__global__ __launch_bounds__(256) void qk_post(const float* __restrict__ qkv,
                                               const float* __restrict__ gq,
                                               const float* __restrict__ gk,
                                               BF16* __restrict__ Qb, BF16* __restrict__ Kb,
                                               const float* __restrict__ vfreq,
                                               const float* __restrict__ afreq, int l) {
  int r = blockIdx.x;
  int which = blockIdx.y;
  const float* src = qkv + (size_t)r * 3072 + which * 1024;
  int e = (r >= 2048) ? 1 : 0;
  const float* g = (which ? gk : gq) + (size_t)(e * 2 + l) * 1024;
  BF16* dst = which ? Kb : Qb;
  const float* fr = e ? (afreq + (size_t)(r - 2048) * 32) : (vfreq + (size_t)r * 32);
  float4 v = ((const float4*)src)[threadIdx.x];
  float s2 = v.x * v.x + v.y * v.y + v.z * v.z + v.w * v.w;
#pragma unroll
  for (int off = 32; off >= 1; off >>= 1) s2 += __shfl_down(s2, off);
  __shared__ float red[4];
  int lane = threadIdx.x & 63, w = threadIdx.x >> 6;
  if (lane == 0) red[w] = s2;
  __syncthreads();
  s2 = red[0] + red[1] + red[2] + red[3];
  float inv = rsqrtf(s2 * (1.f / 1024.f) + 1e-6f);
  if (which == 0) inv *= 0.125f * 1.44269504f;  // fold softmax scale into Q
  int c = threadIdx.x * 4;
  float xe0 = v.x * inv * g[c], xo0 = v.y * inv * g[c + 1];
  float xe1 = v.z * inv * g[c + 2], xo1 = v.w * inv * g[c + 3];
  int p0 = (c & 63) >> 1;
  float c0, s0, c1, s1;
  __sincosf(fr[p0], &s0, &c0);
  __sincosf(fr[p0 + 1], &s1, &c1);
  int h = c >> 6;
  size_t o = ((size_t)h * 2560 + r) * 64 + (c & 63);
  dst[o + 0] = __float2bfloat16(xe0 * c0 - xo0 * s0);
  dst[o + 1] = __float2bfloat16(xe0 * s0 + xo0 * c0);
  dst[o + 2] = __float2bfloat16(xe1 * c1 - xo1 * s1);
  dst[o + 3] = __float2bfloat16(xe1 * s1 + xo1 * c1);
}

// ---------------- V (from qkv col 2048, stride 3072) -> V^T (H*DH, S) bf16 ----------------
__global__ __launch_bounds__(256) void vpost(const float* __restrict__ qkv,
                                             BF16* __restrict__ VT) {
  __shared__ float t[32][33];
  int r0 = blockIdx.x * 32, c0 = blockIdx.y * 32;
  int tx = threadIdx.x & 31, ty = threadIdx.x >> 5;
#pragma unroll
  for (int i = 0; i < 4; i++)
    t[ty + 8 * i][tx] = qkv[(size_t)(r0 + ty + 8 * i) * 3072 + 2048 + c0 + tx];
  __syncthreads();
#pragma unroll
  for (int i = 0; i < 4; i++)
    VT[(size_t)(c0 + ty + 8 * i) * 2560 + r0 + tx] = __float2bfloat16(t[tx][ty + 8 * i]);
}

// ---------------- GEMM v5: 128x64 tile, BK=64, single-buffer, high block count ----------
// C = A(2560xK) * B^T(NxK), expert-aware. LDS 24KB -> 6 blocks/CU.
// EPI: 0 = f32 out +bias, 1 = gelu->bf16 +bias, 3 = bf16 split-K partials (no bias)
template <int EPI, int KS>
__global__ __launch_bounds__(256) void gemm2(const BF16* __restrict__ A,
                                             const BF16* __restrict__ Bw, size_t Bestride,
                                             const float* __restrict__ bias, int biasE,
                                             void* __restrict__ out, BF16* __restrict__ part,
                                             int N, int K) {
  __shared__ BF16 As[128 * 64];
  __shared__ BF16 Bs[64 * 64];
  int flat = blockIdx.x + blockIdx.y * gridDim.x;
  int xcd = flat & 7, slot = flat >> 3;
  int bx = slot % gridDim.x;
  int by = (slot / gridDim.x) * 8 + xcd;
  int m0 = bx * 128, n0 = by * 64;
  int e = (m0 >= 2048);
  const BF16* Ab = A + (size_t)m0 * K;
  const BF16* Bb = Bw + (e ? Bestride : 0) + (size_t)n0 * K;
  int kz0 = blockIdx.z * (K / KS), kz1 = kz0 + K / KS;
  int tid = threadIdx.x, lane = tid & 63, w = tid >> 6;
  int wr = w & 1, wc = w >> 1;
  int m15 = lane & 15, q4 = lane >> 4;
  int LA[4], rA[4], cA[4];
#pragma unroll
  for (int i = 0; i < 4; i++) {
    LA[i] = w * 256 + i * 64 + lane;
    rA[i] = LA[i] >> 3;
    cA[i] = (LA[i] & 7) ^ (rA[i] & 7);
  }
  int LB[2], rB[2], cB[2];
#pragma unroll
  for (int i = 0; i < 2; i++) {
    LB[i] = w * 128 + i * 64 + lane;
    rB[i] = LB[i] >> 3;
    cB[i] = (LB[i] & 7) ^ (rB[i] & 7);
  }
  f32x4 acc[4][2] = {};
  for (int k0 = kz0; k0 < kz1; k0 += 64) {
    __syncthreads();
#pragma unroll
    for (int i = 0; i < 4; i++)
      async16(Ab + (size_t)rA[i] * K + k0 + cA[i] * 8, &As[LA[i] * 8]);
#pragma unroll
    for (int i = 0; i < 2; i++)
      async16(Bb + (size_t)rB[i] * K + k0 + cB[i] * 8, &Bs[LB[i] * 8]);
    __syncthreads();
#pragma unroll
    for (int kk = 0; kk < 2; kk++) {
      int pos = ((kk * 4 + q4) ^ (m15 & 7)) * 8;
      bf16x8 af[4], bv[2];
#pragma unroll
      for (int i = 0; i < 4; i++)
        af[i] = *(const bf16x8*)&As[(wr * 64 + i * 16 + m15) * 64 + pos];
#pragma unroll
      for (int j = 0; j < 2; j++)
        bv[j] = *(const bf16x8*)&Bs[(wc * 32 + j * 16 + m15) * 64 + pos];
#pragma unroll
      for (int i = 0; i < 4; i++)
#pragma unroll
        for (int j = 0; j < 2; j++)
          acc[i][j] = MFMA16(af[i], bv[j], acc[i][j]);
    }
  }
#pragma unroll
  for (int i = 0; i < 4; i++) {
    int row = m0 + wr * 64 + 16 * i + q4 * 4;
#pragma unroll
    for (int j = 0; j < 2; j++) {
      int col = n0 + wc * 32 + 16 * j + m15;
      float b = (EPI == 3) ? 0.f : bias[e * biasE + col];
#pragma unroll
      for (int rg = 0; rg < 4; rg++) {
        float v = acc[i][j][rg] + b;
        size_t idx = (size_t)(row + rg) * N + col;
        if (EPI == 0) {
          ((float*)out)[idx] = v;
        } else if (EPI == 1) {
          // gelu(tanh) == v / (1 + exp2(-2*log2e*u)); exact at +-inf, monotone
          float u = v * (0.7978845608f + 0.0356774081f * v * v);
          float d = 1.f + exp2f(-2.8853900818f * u);
          ((BF16*)out)[idx] = __float2bfloat16(v * __builtin_amdgcn_rcpf(d));
        } else {
          part[(size_t)blockIdx.z * 2560 * N + idx] = __float2bfloat16(v);
        }
      }
    }
  }
}

// ---------------- split-K combine (bf16 partials) + gated residual (+ fused LN) ----------------
template <int KS, int LN>
__global__ __launch_bounds__(256) void combine_ln(const BF16* __restrict__ part,
                                                  const float* __restrict__ biasL,
                                                  const float* __restrict__ modp,
                                                  int gi, int lg, int ll, int ish, int isc,
                                                  const float* __restrict__ tmv,
                                                  const float* __restrict__ tma,
                                                  const float* __restrict__ xinV,
                                                  const float* __restrict__ xinA,
                                                  float* __restrict__ xout,
                                                  BF16* __restrict__ lnout) {
  int r = blockIdx.x, e = (r >= 2048) ? 1 : 0;
  int c = threadIdx.x * 4;
  float4 s = {0.f, 0.f, 0.f, 0.f};
#pragma unroll
  for (int z = 0; z < KS; z++) {
    short4 p4 = *(const short4*)&part[((size_t)z * 2560 + r) * 1024 + c];
    s.x += bf2f(p4.x); s.y += bf2f(p4.y); s.z += bf2f(p4.z); s.w += bf2f(p4.w);
  }
  float4 b = *(const float4*)&biasL[e * 2048 + c];
  const float* tm = e ? tma : tmv;
  float4 gm = *(const float4*)&modp[(size_t)((e * 2 + lg) * 6 + gi) * 1024 + c];
  float4 gt = *(const float4*)&tm[gi * 1024 + c];
  const float* xrow = e ? (xinA + (size_t)(r - 2048) * 1024) : (xinV + (size_t)r * 1024);
  float4 xi = *(const float4*)&xrow[c];
  float4 o;
  o.x = xi.x + (gm.x + gt.x) * (s.x + b.x);
  o.y = xi.y + (gm.y + gt.y) * (s.y + b.y);
  o.z = xi.z + (gm.z + gt.z) * (s.z + b.z);
  o.w = xi.w + (gm.w + gt.w) * (s.w + b.w);
  *(float4*)&xout[(size_t)r * 1024 + c] = o;
  if (LN) {
    float su = o.x + o.y + o.z + o.w;
    float s2 = o.x * o.x + o.y * o.y + o.z * o.z + o.w * o.w;
#pragma unroll
    for (int off = 32; off >= 1; off >>= 1) {
      su += __shfl_down(su, off);
      s2 += __shfl_down(s2, off);
    }
    __shared__ float red[8];
    int lane = threadIdx.x & 63, w = threadIdx.x >> 6;
    if (lane == 0) { red[w] = su; red[4 + w] = s2; }
    __syncthreads();
    su = red[0] + red[1] + red[2] + red[3];
    s2 = red[4] + red[5] + red[6] + red[7];
    float mu = su * (1.f / 1024.f);
    float var = s2 * (1.f / 1024.f) - mu * mu;
    float inv = rsqrtf(var + 1e-6f);
    const float* mo = modp + (size_t)((e * 2 + ll) * 6) * 1024;
    BF16* ob = lnout + (size_t)r * 1024 + c;
    float ov[4] = {o.x, o.y, o.z, o.w};
#pragma unroll
    for (int k = 0; k < 4; k++) {
      float sc = mo[isc * 1024 + c + k] + tm[isc * 1024 + c + k];
      float sh = mo[ish * 1024 + c + k] + tm[ish * 1024 + c + k];
      ob[k] = __float2bfloat16((ov[k] - mu) * inv * (1.f + sc) + sh);
    }
  }
}

// ---------------- flash v6: 4-way KV split, bf16 partials via LDS repack ----------------
// Qb (pre-scaled),Kb: (H,S,DH) bf16; VT: (H,DH,S) bf16
// grid (40, 16, 4): z = KV quarter. Unnormalized O (bf16) + (m,l f32) partials in qkv scratch.
// LDS = 16K(K) + 16K(V) + 8K(P) = 40960 -> 4 blocks/CU.
__global__ __launch_bounds__(256) void flash6(const BF16* __restrict__ Qb,
                                              const BF16* __restrict__ Kb,
                                              const BF16* __restrict__ VT,
                                              BF16* __restrict__ Opb,
                                              float* __restrict__ ml) {
  const int S = 2560;
  const size_t ZOb = 16ull * 40 * 4096;  // bf16 elements per z-slab
  const size_t ZM = 16ull * 40 * 128;    // f32 per z-slab
  __shared__ BF16 Ks[2][64 * 64];
  __shared__ BF16 Vs[2][64 * 64];
  __shared__ BF16 Ps[4][16 * 64];  // wave-private P, stride 64, XOR-swizzled
  int tid = threadIdx.x, lane = tid & 63, w = tid >> 6;
  int h = blockIdx.y, q0 = blockIdx.x * 64, kz = blockIdx.z;
  int m15 = lane & 15, q4 = lane >> 4;
  int actq = (q0 >= 2048);
  int nt = actq ? ((q0 >> 6) + 1) : 32;
  int tb = (kz * nt) >> 2, te = ((kz + 1) * nt) >> 2;
  const BF16* qrow = Qb + ((size_t)h * S + q0 + w * 16 + m15) * 64;
  bf16x8 qf0 = *(const bf16x8*)(qrow + q4 * 8);
  bf16x8 qf1 = *(const bf16x8*)(qrow + 32 + q4 * 8);
  const BF16* kbase = Kb + (size_t)h * S * 64;
  const BF16* vbase = VT + (size_t)h * 64 * S;
  // staging: 64x64 tile = 512 chunks; 2 per thread
  int L0 = w * 128 + lane, L1 = L0 + 64;
  int r0 = L0 >> 3, c0 = (L0 & 7) ^ (r0 & 7);
  int r1 = L1 >> 3, c1 = (L1 & 7) ^ (r1 & 7);
  {
    const BF16* kg = kbase + (size_t)tb * 64 * 64;
    const BF16* vg = vbase + (size_t)tb * 64;
    async16(kg + (size_t)r0 * 64 + c0 * 8, &Ks[0][L0 * 8]);
    async16(kg + (size_t)r1 * 64 + c1 * 8, &Ks[0][L1 * 8]);
    async16(vg + (size_t)r0 * S + c0 * 8, &Vs[0][L0 * 8]);
    async16(vg + (size_t)r1 * S + c1 * 8, &Vs[0][L1 * 8]);
  }
  f32x4 oa[4] = {};
  float m_i = -1e30f, l_i = 0.f;  // l_i: per-lane partial (reduced at end)
  int colq = q0 + w * 16 + m15;
  char* Pw = (char*)&Ps[w][0];
  int prow = m15 * 128;            // byte offset of this q's P row
  int pswz = (m15 & 7) << 4;       // XOR swizzle (bits 4-6 of row-local byte)
  int x0 = (q4 ^ (m15 & 7)) * 8, x1 = ((4 + q4) ^ (m15 & 7)) * 8;
  __syncthreads();
  for (int t = tb; t < te; t++) {
    int cur = (t - tb) & 1;
    if (t + 1 < te) {
      int nb = cur ^ 1;
      const BF16* kg = kbase + (size_t)(t + 1) * 64 * 64;
      const BF16* vg = vbase + (size_t)(t + 1) * 64;
      async16(kg + (size_t)r0 * 64 + c0 * 8, &Ks[nb][L0 * 8]);
      async16(kg + (size_t)r1 * 64 + c1 * 8, &Ks[nb][L1 * 8]);
      async16(vg + (size_t)r0 * S + c0 * 8, &Vs[nb][L0 * 8]);
      async16(vg + (size_t)r1 * S + c1 * 8, &Vs[nb][L1 * 8]);
    }
    // S^T = K * Q^T (col = q = m15, row = kv)
    f32x4 st[4];
    __builtin_amdgcn_s_setprio(1);
#pragma unroll
    for (int jt = 0; jt < 4; jt++) {
      int row = (jt * 16 + m15) * 64;
      bf16x8 kf0 = *(const bf16x8*)&Ks[cur][row + x0];
      bf16x8 kf1 = *(const bf16x8*)&Ks[cur][row + x1];
      f32x4 zz = {};
      zz = MFMA16(kf0, qf0, zz);
      st[jt] = MFMA16(kf1, qf1, zz);
    }
    __builtin_amdgcn_s_setprio(0);
    float mx = -1e30f;  // per-lane max (covers this lane's 16 scores)
    if (actq && t == nt - 1) {
#pragma unroll
      for (int jt = 0; jt < 4; jt++)
#pragma unroll
        for (int rg = 0; rg < 4; rg++) {
          int rowkv = t * 64 + jt * 16 + q4 * 4 + rg;
          if (rowkv > colq) st[jt][rg] = -1e30f;
          mx = fmaxf(mx, st[jt][rg]);
        }
    } else {
#pragma unroll
      for (int jt = 0; jt < 4; jt++) {
        mx = fmaxf(fmaxf(mx, st[jt][0]), st[jt][1]);  // v_max3
        mx = fmaxf(fmaxf(mx, st[jt][2]), st[jt][3]);
      }
    }
    // defer-max: lane-local check is sufficient (union of lanes covers each row).
    if (!__all(mx <= m_i + 8.f)) {
      float m2 = fmaxf(mx, __shfl_xor(mx, 16));
      m2 = fmaxf(m2, __shfl_xor(m2, 32));
      float mn = fmaxf(m_i, m2);
      float al = exp2f(m_i - mn);
      m_i = mn;
      l_i *= al;
      float alr[4];
#pragma unroll
      for (int rg = 0; rg < 4; rg++) alr[rg] = __shfl(al, q4 * 4 + rg);
#pragma unroll
      for (int dt = 0; dt < 4; dt++)
#pragma unroll
        for (int rg = 0; rg < 4; rg++) oa[dt][rg] *= alr[rg];
    }
    float rs = 0.f;
#pragma unroll
    for (int jt = 0; jt < 4; jt++) {
      float p0 = exp2f(st[jt][0] - m_i), p1 = exp2f(st[jt][1] - m_i);
      float p2 = exp2f(st[jt][2] - m_i), p3 = exp2f(st[jt][3] - m_i);
      rs += (p0 + p1) + (p2 + p3);
      uint2 pr = {pkbf(p0, p1), pkbf(p2, p3)};
      *(uint2*)(Pw + prow + ((jt * 32 + q4 * 8) ^ pswz)) = pr;  // P[q][kv], b64
    }
    l_i += rs;
    // O += P * V  (A = P from wave-private swizzled LDS, B = V^T rows)
    bf16x8 pf0 = *(const bf16x8*)(Pw + prow + ((q4 * 16) ^ pswz));
    bf16x8 pf1 = *(const bf16x8*)(Pw + prow + ((64 + q4 * 16) ^ pswz));
    __builtin_amdgcn_s_setprio(1);
#pragma unroll
    for (int dt = 0; dt < 4; dt++) {
      int vr = (dt * 16 + m15) * 64;
      bf16x8 vf0 = *(const bf16x8*)&Vs[cur][vr + x0];
      bf16x8 vf1 = *(const bf16x8*)&Vs[cur][vr + x1];
      oa[dt] = MFMA16(pf0, vf0, oa[dt]);
      oa[dt] = MFMA16(pf1, vf1, oa[dt]);
    }
    __builtin_amdgcn_s_setprio(0);
    __syncthreads();
  }
  // reduce partial l across the q-group
  l_i += __shfl_xor(l_i, 16);
  l_i += __shfl_xor(l_i, 32);
  if (q4 == 0) {
    float* mp = ml + (size_t)kz * ZM + ((size_t)h * 40 + blockIdx.x) * 128;
    mp[w * 16 + m15] = m_i;
    mp[64 + w * 16 + m15] = l_i;
  }
  // repack partial O f32->bf16 through dead Ks area ([64][72] stride, bank-spread),
  // then coalesced 16B copy-out. Saves half the partial HBM traffic vs f32.
  BF16* rp = &Ks[0][0];  // 64*72*2 = 9216 B <= 16 KB
#pragma unroll
  for (int dt = 0; dt < 4; dt++)
#pragma unroll
    for (int rg = 0; rg < 4; rg++)
      rp[(w * 16 + q4 * 4 + rg) * 72 + dt * 16 + m15] = __float2bfloat16(oa[dt][rg]);
  __syncthreads();
  BF16* Opz = Opb + (size_t)kz * ZOb + ((size_t)h * 40 + blockIdx.x) * 4096;
#pragma unroll
  for (int kk = 0; kk < 2; kk++) {
    int k = tid * 2 + kk;
    int row = k >> 3, ci = k & 7;
    uint4 d = *(const uint4*)&rp[row * 72 + ci * 8];
    *(uint4*)&Opz[(size_t)row * 64 + ci * 8] = d;
  }
}

// ---------------- merge the four KV-quarter bf16 partials -> Obf bf16 ----------------
__global__ __launch_bounds__(256) void fcomb4b(const BF16* __restrict__ Opb,
                                               const float* __restrict__ ml,
                                               BF16* __restrict__ O) {
  int qt = blockIdx.x, h = blockIdx.y;
  int q = threadIdx.x >> 2;          // 0..63
  int d0 = (threadIdx.x & 3) * 16;   // 16 elements per thread
  const size_t ZOb = 16ull * 40 * 4096;
  const size_t ZM = 16ull * 40 * 128;
  size_t tile = (size_t)h * 40 + qt;
  size_t base = tile * 4096 + (size_t)q * 64 + d0;
  size_t mb = tile * 128 + q;
  float m[4], lv[4];
#pragma unroll
  for (int z = 0; z < 4; z++) {
    m[z] = ml[z * ZM + mb];
    lv[z] = ml[z * ZM + mb + 64];
  }
  float M = fmaxf(fmaxf(m[0], m[1]), fmaxf(m[2], m[3]));
  float wz[4];
  float den = 0.f;
#pragma unroll
  for (int z = 0; z < 4; z++) {
    wz[z] = exp2f(m[z] - M);
    den += wz[z] * lv[z];
  }
  float r = 1.f / den;
#pragma unroll
  for (int z = 0; z < 4; z++) wz[z] *= r;
  float acc[16] = {};
#pragma unroll
  for (int z = 0; z < 4; z++) {
    const BF16* P = Opb + z * ZOb + base;
    bf16x8 a = *(const bf16x8*)P;
    bf16x8 b = *(const bf16x8*)(P + 8);
#pragma unroll
    for (int i = 0; i < 8; i++) {
      acc[i] += wz[z] * bf2f(a[i]);
      acc[8 + i] += wz[z] * bf2f(b[i]);
    }
  }
  BF16* orow = O + (size_t)(qt * 64 + q) * 1024 + h * 64 + d0;
  u32 pk[8];
#pragma unroll
  for (int i = 0; i < 8; i++) pk[i] = pkbf(acc[2 * i], acc[2 * i + 1]);
  *(uint4*)&orow[0] = *(uint4*)&pk[0];
  *(uint4*)&orow[8] = *(uint4*)&pk[4];
}

// ---------------- host ----------------
extern "C" void kernel_launch(void* const* d_in, const int* in_sizes, int n_in,
                              void* d_out, int out_size, void* d_ws, size_t ws_size,
                              hipStream_t stream) {
  (void)in_sizes; (void)n_in; (void)out_size; (void)ws_size;
  const float* vid  = (const float*)d_in[0];
  const float* act  = (const float*)d_in[1];
  const float* vfr  = (const float*)d_in[2];
  const float* afr  = (const float*)d_in[3];
  const float* tmv  = (const float*)d_in[4];
  const float* tma  = (const float*)d_in[5];
  const float* Wq   = (const float*)d_in[6];
  const float* Wk   = (const float*)d_in[7];
  const float* Wv   = (const float*)d_in[8];
  const float* Wo   = (const float*)d_in[9];
  const float* bq   = (const float*)d_in[10];
  const float* bk   = (const float*)d_in[11];
  const float* bv   = (const float*)d_in[12];
  const float* bo   = (const float*)d_in[13];
  const float* gq   = (const float*)d_in[14];
  const float* gk   = (const float*)d_in[15];
  const float* modp = (const float*)d_in[16];
  const float* W1   = (const float*)d_in[17];
  const float* b1   = (const float*)d_in[18];
  const float* W2   = (const float*)d_in[19];
  const float* b2   = (const float*)d_in[20];

  char* p = (char*)d_ws;
  auto carve = [&](size_t bytes) {
    char* r = p;
    p += (bytes + 255) & ~(size_t)255;
    return r;
  };
  BF16* WqkvT = (BF16*)carve(4ull * 3072 * 1024 * 2);
  BF16* WoT   = (BF16*)carve(4ull * 1024 * 1024 * 2);
  BF16* W1T   = (BF16*)carve(4ull * 4096 * 1024 * 2);
  BF16* W2T   = (BF16*)carve(4ull * 1024 * 4096 * 2);
  float* bqkv = (float*)carve(4ull * 3072 * 4);
  float* x    = (float*)carve(2560ull * 1024 * 4);
  BF16* abf   = (BF16*)carve(2560ull * 1024 * 2);
  float* qkv  = (float*)carve(2560ull * 3072 * 4);
  BF16* Qb    = (BF16*)carve(2560ull * 1024 * 2);
  BF16* Kb    = (BF16*)carve(2560ull * 1024 * 2);
  BF16* part = (BF16*)qkv;  // GEMM split-K bf16 partials alias qkv (dead then)
  const size_t ZOb = 16ull * 40 * 4096;
  BF16* Opb = (BF16*)qkv;                              // flash bf16 partials: 4 x 5.24MB
  float* mlb = (float*)((char*)qkv + 4ull * ZOb * 2);  // + 1.3MB, inside qkv region
  BF16* VTb   = (BF16*)carve(2560ull * 1024 * 2);
  BF16* Obf   = (BF16*)carve(2560ull * 1024 * 2);
  BF16* mibf  = (BF16*)carve(2560ull * 1024 * 2);
  BF16* hbf   = (BF16*)carve(2560ull * 4096 * 2);

  const size_t S3 = 3072ull * 1024;
  wtransq<<<dim3(32, 32, 12), 256, 0, stream>>>(Wq, Wk, Wv, WqkvT);
  wtrans<<<dim3(32, 32, 4), 256, 0, stream>>>(Wo, WoT, 1024, 1024, 1024ull * 1024);
  wtrans<<<dim3(128, 32, 4), 256, 0, stream>>>(W1, W1T, 1024, 4096, 4096ull * 1024);
  wtrans<<<dim3(32, 128, 4), 256, 0, stream>>>(W2, W2T, 4096, 1024, 1024ull * 4096);
  packb<<<48, 256, 0, stream>>>(bq, bk, bv, bqkv);

  // layer-0 first LN reads the original inputs directly (x materialized by combine_ln)
  ln_mod<<<2560, 256, 0, stream>>>(vid, act, abf, modp, tmv, tma, 0, 0, 1);

  for (int l = 0; l < 2; l++) {
    // QKV: 128x64 tiles -> (20,48) = 960 blocks, direct f32 + bias
    gemm2<0, 1><<<dim3(20, 48, 1), 256, 0, stream>>>(
        abf, WqkvT + (size_t)l * S3, 2 * S3, bqkv + l * 3072, 6144, qkv, nullptr, 3072, 1024);
    qk_post<<<dim3(2560, 2), 256, 0, stream>>>(qkv, gq, gk, Qb, Kb, vfr, afr, l);
    vpost<<<dim3(80, 32), 256, 0, stream>>>(qkv, VTb);
    flash6<<<dim3(40, 16, 4), 256, 0, stream>>>(Qb, Kb, VTb, Opb, mlb);
    fcomb4b<<<dim3(40, 16), 256, 0, stream>>>(Opb, mlb, Obf);
    // Wo: (20,16,2) = 640 blocks, bf16 split-K partials
    gemm2<3, 2><<<dim3(20, 16, 2), 256, 0, stream>>>(
        Obf, WoT + (size_t)l * 1024 * 1024, 2ull * 1024 * 1024, nullptr, 0, nullptr, part,
        1024, 1024);
    // residual + gate, then fused LN for the MLP input
    combine_ln<2, 1><<<2560, 256, 0, stream>>>(
        part, bo + l * 1024, modp, 2, l, l, 3, 4, tmv, tma,
        (l == 0) ? vid : x, (l == 0) ? act : (x + 2048ull * 1024), x, mibf);
    // W1: (20,64) = 1280 blocks, gelu epilogue
    gemm2<1, 1><<<dim3(20, 64, 1), 256, 0, stream>>>(
        mibf, W1T + (size_t)l * 4096 * 1024, 2ull * 4096 * 1024, b1 + l * 4096, 8192, hbf,
        nullptr, 4096, 1024);
    // W2: (20,16,4) = 1280 blocks, bf16 split-K partials
    gemm2<3, 4><<<dim3(20, 16, 4), 256, 0, stream>>>(
        hbf, W2T + (size_t)l * 4096 * 1024, 2ull * 4096 * 1024, nullptr, 0, nullptr, part,
        1024, 4096);
    if (l == 0) {
      // residual + gate, then fused LN1 of layer 1
      combine_ln<4, 1><<<2560, 256, 0, stream>>>(
          part, b2, modp, 5, 0, 1, 0, 1, tmv, tma, x, x + 2048ull * 1024, x, abf);
    } else {
      combine_ln<4, 0><<<2560, 256, 0, stream>>>(
          part, b2 + 1024, modp, 5, 1, 0, 0, 0, tmv, tma, x, x + 2048ull * 1024,
          (float*)d_out, nullptr);
    }
  }
}